// Round 2
// baseline (323.660 us; speedup 1.0000x reference)
//
#include <hip/hip_runtime.h>
#include <cstdint>

#define F_IN  8
#define HID   64
#define F_OUTD 8
#define RDIM  256
#define CDIM  4096
#define NSETS 3
#define NIND  4096
#define MDIM  4096
#define G     4      // samples (m-values) per thread

// ---------------- zero fill (graph-capture-safe memset) ----------------
__global__ void zero_kernel(float4* __restrict__ p, int n4) {
    int i = blockIdx.x * blockDim.x + threadIdx.x;
    if (i < n4) p[i] = make_float4(0.f, 0.f, 0.f, 0.f);
}

// ---------------- batched tiled transpose: src [F][M][N] -> dst [F][N][M] ----
__global__ void transpose_f(const float* __restrict__ src, float* __restrict__ dst,
                            int M, int N) {
    __shared__ float tile[32][33];
    int f = blockIdx.z;
    const float* s = src + (size_t)f * M * N;
    float*       d = dst + (size_t)f * M * N;
    int n0 = blockIdx.x * 32, m0 = blockIdx.y * 32;
    int tx = threadIdx.x, ty = threadIdx.y;   // block (32, 8)
#pragma unroll
    for (int i = 0; i < 32; i += 8)
        tile[ty + i][tx] = s[(size_t)(m0 + ty + i) * N + n0 + tx];
    __syncthreads();
#pragma unroll
    for (int i = 0; i < 32; i += 8)
        d[(size_t)(n0 + ty + i) * M + m0 + tx] = tile[tx][ty + i];
}

// ---------------- build inverse permutations of col0 ----------------
// inv[si][c0] = k  such that ind_i[s][k][0] == c0       (si = s*3+i)
__global__ void build_inv(const int* __restrict__ ind0, const int* __restrict__ ind1,
                          const int* __restrict__ ind2, int* __restrict__ inv) {
    int k  = blockIdx.x * 256 + threadIdx.x;
    int si = blockIdx.y;
    int s_ = si / 3, i_ = si % 3;
    const int* ind = (i_ == 0 ? ind0 : (i_ == 1 ? ind1 : ind2)) + (size_t)s_ * NIND * 2;
    int c0 = ind[2 * k];
    inv[(size_t)si * NIND + c0] = k;
}

// ---------------- build gather/scatter column tables ----------------
// g[si][m] = col1[ inv[ mi ] ]  (source column, via inverse perm — project())
// h[si][m] = col1[ mi ]         (dest column, direct indexing — scatter idx)
__global__ void build_gh(const int* __restrict__ ind0, const int* __restrict__ ind1,
                         const int* __restrict__ ind2, const int* __restrict__ mix,
                         const int* __restrict__ inv,
                         int* __restrict__ g, int* __restrict__ h) {
    int m  = blockIdx.x * 256 + threadIdx.x;
    int si = blockIdx.y;
    int s_ = si / 3, i_ = si % 3;
    const int* ind = (i_ == 0 ? ind0 : (i_ == 1 ? ind1 : ind2)) + (size_t)s_ * NIND * 2;
    int mi = mix[(size_t)si * MDIM + m];
    h[(size_t)si * MDIM + m] = ind[2 * mi + 1];
    int k = inv[(size_t)si * NIND + mi];
    g[(size_t)si * MDIM + m] = ind[2 * k + 1];
}

// ---------------- fused gather -> MLP -> amax scatter ----------------
// One block per (s, 4 consecutive m): 256 threads = r. Each thread evaluates the
// MLP for G=4 samples with interleaved accumulators (4 independent FMA chains).
// inT is [f][c][r]; outT is [f][c][r] uint-punned.
__global__ __launch_bounds__(256, 2)
void mlp_scatter(const float* __restrict__ inT,
                 const float* __restrict__ w1, const float* __restrict__ b1,
                 const float* __restrict__ w2, const float* __restrict__ b2,
                 const int* __restrict__ g, const int* __restrict__ h,
                 unsigned int* __restrict__ outT) {
    __shared__ float sw1[HID * 24];     // [j][k] row-major (96B rows, float4-aligned)
    __shared__ float sw2[HID * F_OUTD]; // transposed: [j][f]
    __shared__ float sb1[HID];
    __shared__ float sb2[F_OUTD];
    __shared__ int   sg[G][3], sh[G][3];

    int t = threadIdx.x;
    for (int idx = t; idx < HID * 24; idx += 256) sw1[idx] = w1[idx];
    for (int idx = t; idx < HID * F_OUTD; idx += 256) {
        int f = idx >> 6, j = idx & 63;
        sw2[j * F_OUTD + f] = w2[idx];
    }
    if (t < HID)    sb1[t] = b1[t];
    if (t < F_OUTD) sb2[t] = b2[t];

    int bx = blockIdx.x;
    int s_ = bx >> 10;               // / (MDIM/G)
    int mg = (bx & 1023) * G;
    if (t < 12) {
        int u = t & 3, i_ = t >> 2;
        sg[u][i_] = g[((size_t)s_ * 3 + i_) * MDIM + mg + u];
    } else if (t < 24) {
        int q = t - 12;
        int u = q & 3, i_ = q >> 2;
        sh[u][i_] = h[((size_t)s_ * 3 + i_) * MDIM + mg + u];
    }
    __syncthreads();

    int r = t;
    // gather 24 features per sample: c[u][i*8+f] = input[f, r, g_i] (coalesced over r)
    float c[G][24];
#pragma unroll
    for (int u = 0; u < G; u++) {
#pragma unroll
        for (int i = 0; i < 3; i++) {
            const float* base = inT + (size_t)sg[u][i] * RDIM + r;
#pragma unroll
            for (int f = 0; f < F_IN; f++)
                c[u][i * 8 + f] = base[(size_t)f * (CDIM * RDIM)];
        }
    }

    float of[G][F_OUTD];
#pragma unroll
    for (int u = 0; u < G; u++)
#pragma unroll
        for (int f = 0; f < F_OUTD; f++) of[u][f] = sb2[f];

#pragma unroll 2
    for (int j = 0; j < HID; j++) {
        const float4* wr = (const float4*)&sw1[j * 24];
        float4 w0 = wr[0], w1v = wr[1], w2v = wr[2], w3 = wr[3], w4 = wr[4], w5 = wr[5];
        float a[G];
        float bj = sb1[j];
#pragma unroll
        for (int u = 0; u < G; u++) a[u] = bj;
        // 4 independent accumulation chains at every issue slot
#pragma unroll
        for (int u = 0; u < G; u++) { a[u] += w0.x * c[u][0];  a[u] += w0.y * c[u][1];  a[u] += w0.z * c[u][2];  a[u] += w0.w * c[u][3]; }
#pragma unroll
        for (int u = 0; u < G; u++) { a[u] += w1v.x * c[u][4]; a[u] += w1v.y * c[u][5]; a[u] += w1v.z * c[u][6]; a[u] += w1v.w * c[u][7]; }
#pragma unroll
        for (int u = 0; u < G; u++) { a[u] += w2v.x * c[u][8]; a[u] += w2v.y * c[u][9]; a[u] += w2v.z * c[u][10]; a[u] += w2v.w * c[u][11]; }
#pragma unroll
        for (int u = 0; u < G; u++) { a[u] += w3.x * c[u][12]; a[u] += w3.y * c[u][13]; a[u] += w3.z * c[u][14]; a[u] += w3.w * c[u][15]; }
#pragma unroll
        for (int u = 0; u < G; u++) { a[u] += w4.x * c[u][16]; a[u] += w4.y * c[u][17]; a[u] += w4.z * c[u][18]; a[u] += w4.w * c[u][19]; }
#pragma unroll
        for (int u = 0; u < G; u++) { a[u] += w5.x * c[u][20]; a[u] += w5.y * c[u][21]; a[u] += w5.z * c[u][22]; a[u] += w5.w * c[u][23]; }
#pragma unroll
        for (int u = 0; u < G; u++) a[u] = fmaxf(a[u], 0.f);

        float4 wa = ((const float4*)&sw2[j * F_OUTD])[0];
        float4 wb = ((const float4*)&sw2[j * F_OUTD])[1];
#pragma unroll
        for (int u = 0; u < G; u++) {
            of[u][0] += a[u] * wa.x; of[u][1] += a[u] * wa.y;
            of[u][2] += a[u] * wa.z; of[u][3] += a[u] * wa.w;
            of[u][4] += a[u] * wb.x; of[u][5] += a[u] * wb.y;
            of[u][6] += a[u] * wb.z; of[u][7] += a[u] * wb.w;
        }
    }

    // amax scatter; output >= 0 always (include_self over zeros) so clamp at 0
    // and use uint-punned atomicMax (monotone for nonneg IEEE floats).
#pragma unroll
    for (int u = 0; u < G; u++) {
#pragma unroll
        for (int i = 0; i < 3; i++) {
            int col = sh[u][i];
            unsigned int* base = outT + (size_t)col * RDIM + r;
#pragma unroll
            for (int f = 0; f < F_OUTD; f++) {
                float v = of[u][f];
                if (v > 0.f)
                    atomicMax(base + (size_t)f * (CDIM * RDIM), __float_as_uint(v));
            }
        }
    }
}

extern "C" void kernel_launch(void* const* d_in, const int* in_sizes, int n_in,
                              void* d_out, int out_size, void* d_ws, size_t ws_size,
                              hipStream_t stream) {
    const float* input = (const float*)d_in[0];
    const float* w1    = (const float*)d_in[1];
    const float* b1    = (const float*)d_in[2];
    const float* w2    = (const float*)d_in[3];
    const float* b2    = (const float*)d_in[4];
    const int*   ind0  = (const int*)d_in[5];
    const int*   ind1  = (const int*)d_in[6];
    const int*   ind2  = (const int*)d_in[7];
    const int*   mix   = (const int*)d_in[8];

    char* ws = (char*)d_ws;
    float*        inT  = (float*)ws;                            // 32 MiB
    unsigned int* outT = (unsigned int*)(ws + 33554432ull);     // 32 MiB
    int*          inv  = (int*)(ws + 67108864ull);              // 144 KiB
    int*          g    = (int*)(ws + 67256320ull);              // 144 KiB
    int*          h    = (int*)(ws + 67403776ull);              // 144 KiB

    int n4 = (F_OUTD * RDIM * CDIM) / 4;
    zero_kernel<<<(n4 + 255) / 256, 256, 0, stream>>>((float4*)outT, n4);

    dim3 tb(32, 8);
    transpose_f<<<dim3(CDIM / 32, RDIM / 32, F_IN), tb, 0, stream>>>(input, inT, RDIM, CDIM);

    build_inv<<<dim3(NIND / 256, 9), 256, 0, stream>>>(ind0, ind1, ind2, inv);
    build_gh<<<dim3(MDIM / 256, 9), 256, 0, stream>>>(ind0, ind1, ind2, mix, inv, g, h);

    mlp_scatter<<<NSETS * MDIM / G, 256, 0, stream>>>(inT, w1, b1, w2, b2, g, h, outT);

    transpose_f<<<dim3(RDIM / 32, CDIM / 32, F_OUTD), tb, 0, stream>>>(
        (const float*)outT, (float*)d_out, CDIM, RDIM);
}

// Round 3
// 243.554 us; speedup vs baseline: 1.3289x; 1.3289x over previous
//
#include <hip/hip_runtime.h>
#include <hip/hip_bf16.h>
#include <cstdint>

#define F_IN   8
#define HID    64
#define F_OUTD 8
#define RDIM   256
#define CDIM   4096
#define NSETS  3
#define NIND   4096
#define MDIM   4096

using short8 = __attribute__((ext_vector_type(8))) short;
using f32x4  = __attribute__((ext_vector_type(4))) float;

__device__ inline unsigned short f2bf(float x) {
    union { float f; unsigned int u; } v; v.f = x;
    unsigned int r = v.u + 0x7fffu + ((v.u >> 16) & 1u);   // RNE
    return (unsigned short)(r >> 16);
}
__device__ inline unsigned int packbf(float a, float b) {
    return (unsigned int)f2bf(a) | ((unsigned int)f2bf(b) << 16);
}

// ---------------- zero fill ----------------
__global__ void zero_kernel(float4* __restrict__ p, int n4) {
    int i = blockIdx.x * blockDim.x + threadIdx.x;
    if (i < n4) p[i] = make_float4(0.f, 0.f, 0.f, 0.f);
}

// ---------------- input prep: in [F][R][C] f32 -> inT2 [C][R][F] bf16 ----------
__global__ __launch_bounds__(256)
void prep_in(const float* __restrict__ in, unsigned short* __restrict__ out) {
    const int PADH = 264;                       // halfs per c-row (528B = 33*16)
    __shared__ unsigned short tile[32 * PADH];  // ~16.5 KB
    int c0 = blockIdx.x * 32, r0 = blockIdx.y * 32;
    int t = threadIdx.x;
    int tx = t & 31, ty = t >> 5;               // tx = c-local, ty = r-sub
#pragma unroll
    for (int f = 0; f < 8; f++)
#pragma unroll
        for (int rr = 0; rr < 4; rr++) {
            int r = ty + rr * 8;
            float v = in[((size_t)f * RDIM + (r0 + r)) * CDIM + c0 + tx];
            tile[tx * PADH + r * 8 + f] = f2bf(v);
        }
    __syncthreads();
    int r = t & 31, cl = t >> 5;
#pragma unroll
    for (int cc = 0; cc < 4; cc++) {
        int c = cc * 8 + cl;
        uint4 v = *(const uint4*)&tile[c * PADH + r * 8];
        *(uint4*)(out + (((size_t)(c0 + c) * RDIM) + (r0 + r)) * 8) = v;
    }
}

// ---------------- weight prep: bf16, padded, MFMA-fragment-friendly ----------
// w1bf [64 j][32 k] (k>=24 zero);  w2bf [16 f][64 j] (f>=8 zero)
__global__ void prep_w(const float* __restrict__ w1, const float* __restrict__ w2,
                       unsigned short* __restrict__ w1bf, unsigned short* __restrict__ w2bf) {
    int t = threadIdx.x;
    for (int i = t; i < 64 * 32; i += 256) {
        int j = i >> 5, k = i & 31;
        w1bf[i] = (k < 24) ? f2bf(w1[j * 24 + k]) : 0;
    }
    for (int i = t; i < 16 * 64; i += 256) {
        int f = i >> 6, j = i & 63;
        w2bf[i] = (f < 8) ? f2bf(w2[f * 64 + j]) : 0;
    }
}

// ---------------- build inverse permutations of col0 ----------------
__global__ void build_inv(const int* __restrict__ ind0, const int* __restrict__ ind1,
                          const int* __restrict__ ind2, int* __restrict__ inv) {
    int k  = blockIdx.x * 256 + threadIdx.x;
    int si = blockIdx.y;
    int s_ = si / 3, i_ = si % 3;
    const int* ind = (i_ == 0 ? ind0 : (i_ == 1 ? ind1 : ind2)) + (size_t)s_ * NIND * 2;
    int c0 = ind[2 * k];
    inv[(size_t)si * NIND + c0] = k;
}

// ---------------- build gather/scatter column tables ----------------
__global__ void build_gh(const int* __restrict__ ind0, const int* __restrict__ ind1,
                         const int* __restrict__ ind2, const int* __restrict__ mix,
                         const int* __restrict__ inv,
                         int* __restrict__ g, int* __restrict__ h) {
    int m  = blockIdx.x * 256 + threadIdx.x;
    int si = blockIdx.y;
    int s_ = si / 3, i_ = si % 3;
    const int* ind = (i_ == 0 ? ind0 : (i_ == 1 ? ind1 : ind2)) + (size_t)s_ * NIND * 2;
    int mi = mix[(size_t)si * MDIM + m];
    h[(size_t)si * MDIM + m] = ind[2 * mi + 1];
    int k = inv[(size_t)si * NIND + mi];
    g[(size_t)si * MDIM + m] = ind[2 * k + 1];
}

// ---------------- MFMA MLP + amax scatter ----------------
// One wave per (s,m). Layer1 computed transposed: a1^T[64j][16r] = w1 * c^T.
//   B1-frag (c^T): lane: col r = lane&15, k-group q = lane>>4 -> 16B load
//   straight from inT2[g_q][rt*16 + r][0..8]  (q==3 => zeros, K-pad).
//   A1-frag: w1bf[16t + (lane&15)][8q..8q+8].
// D1 lane layout: col = r, row j = 16t + 4q + reg  (verified C/D mapping).
// Layer2 via 2KB wave-private LDS transpose (XOR-swizzled), then
// out^T[16f][16r] = w2 * a1 with 2 MFMAs (K=64).
__global__ __launch_bounds__(256)
void mlp_mfma(const unsigned short* __restrict__ inT2,
              const unsigned short* __restrict__ w1bf,
              const unsigned short* __restrict__ w2bf,
              const float* __restrict__ b1, const float* __restrict__ b2,
              const int* __restrict__ g, const int* __restrict__ h,
              unsigned int* __restrict__ outT) {
    __shared__ unsigned short lds_all[4][1024];   // 2KB per wave, barrier-free
    int t    = threadIdx.x;
    int wave = t >> 6, lane = t & 63;
    int lo = lane & 15, q = lane >> 4;

    int w_id = blockIdx.x * 4 + wave;     // 0..12287
    int s_   = w_id >> 12;
    int m    = w_id & 4095;

    // constant fragments: A1 (w1), A2 (w2)
    short8 A1[4], A2[2];
#pragma unroll
    for (int tt = 0; tt < 4; tt++)
        A1[tt] = *(const short8*)(w1bf + ((16 * tt + lo) << 5) + (q << 3));
#pragma unroll
    for (int kk = 0; kk < 2; kk++)
        A2[kk] = *(const short8*)(w2bf + (lo << 6) + (kk << 5) + (q << 3));

    // biases in D-layout
    float bb[16];
#pragma unroll
    for (int tt = 0; tt < 4; tt++)
#pragma unroll
        for (int rg = 0; rg < 4; rg++)
            bb[tt * 4 + rg] = b1[16 * tt + 4 * q + rg];
    float b2v[4];
#pragma unroll
    for (int rg = 0; rg < 4; rg++) {
        int f = 4 * q + rg;
        b2v[rg] = (f < 8) ? b2[f] : 0.f;
    }

    // per-m columns
    int gq = (q < 3) ? g[(s_ * 3 + q) * MDIM + m] : 0;
    int h0 = h[(s_ * 3 + 0) * MDIM + m];
    int h1 = h[(s_ * 3 + 1) * MDIM + m];
    int h2 = h[(s_ * 3 + 2) * MDIM + m];

    const unsigned short* src = inT2 + ((size_t)gq * RDIM + lo) * 8;
    char* lds = (char*)lds_all[wave];
    unsigned int swz   = (unsigned int)((lo & 7) << 4);
    unsigned int wbase = (unsigned int)(lo * 128 + q * 8);
    unsigned int rbase = (unsigned int)(lo * 128 + q * 16);

    for (int rt = 0; rt < 16; rt++) {
        // layer-1 B fragment: gathered input (16B coalesced per 16-lane group)
        short8 B1v = {0, 0, 0, 0, 0, 0, 0, 0};
        if (q < 3) B1v = *(const short8*)(src + rt * 128);

        f32x4 acc[4];
#pragma unroll
        for (int tt = 0; tt < 4; tt++) {
            acc[tt][0] = bb[tt * 4 + 0]; acc[tt][1] = bb[tt * 4 + 1];
            acc[tt][2] = bb[tt * 4 + 2]; acc[tt][3] = bb[tt * 4 + 3];
        }
#pragma unroll
        for (int tt = 0; tt < 4; tt++)
            acc[tt] = __builtin_amdgcn_mfma_f32_16x16x32_bf16(A1[tt], B1v, acc[tt], 0, 0, 0);

        // relu + bf16 pack -> swizzled LDS  ( a1 laid out [r=lo][j] )
#pragma unroll
        for (int tt = 0; tt < 4; tt++) {
            float v0 = fmaxf(acc[tt][0], 0.f), v1 = fmaxf(acc[tt][1], 0.f);
            float v2 = fmaxf(acc[tt][2], 0.f), v3 = fmaxf(acc[tt][3], 0.f);
            uint2 dv; dv.x = packbf(v0, v1); dv.y = packbf(v2, v3);
            *(uint2*)(lds + ((wbase + 32 * tt) ^ swz)) = dv;
        }

        // layer-2 B fragments from LDS (conflict-free via matching swizzle)
        short8 B2a = *(const short8*)(lds + (rbase ^ swz));
        short8 B2b = *(const short8*)(lds + ((rbase + 64) ^ swz));

        f32x4 acc2;
#pragma unroll
        for (int rg = 0; rg < 4; rg++) acc2[rg] = b2v[rg];
        acc2 = __builtin_amdgcn_mfma_f32_16x16x32_bf16(A2[0], B2a, acc2, 0, 0, 0);
        acc2 = __builtin_amdgcn_mfma_f32_16x16x32_bf16(A2[1], B2b, acc2, 0, 0, 0);

        // amax scatter: lane holds (r = lo, f = 4q+reg); valid f<8 -> q<2.
        // Output >= 0 (include_self over zeros): clamp at 0, uint-punned atomicMax.
        int rglob = rt * 16 + lo;
        if (q < 2) {
#pragma unroll
            for (int rg = 0; rg < 4; rg++) {
                float v = acc2[rg];
                if (v > 0.f) {
                    unsigned int uv = __float_as_uint(v);
                    size_t bo = (size_t)(4 * q + rg) * (CDIM * RDIM) + rglob;
                    atomicMax(outT + bo + (size_t)h0 * RDIM, uv);
                    atomicMax(outT + bo + (size_t)h1 * RDIM, uv);
                    atomicMax(outT + bo + (size_t)h2 * RDIM, uv);
                }
            }
        }
    }
}

// ---------------- batched tiled transpose: src [F][M][N] -> dst [F][N][M] ----
__global__ void transpose_f(const float* __restrict__ src, float* __restrict__ dst,
                            int M, int N) {
    __shared__ float tile[32][33];
    int f = blockIdx.z;
    const float* s = src + (size_t)f * M * N;
    float*       d = dst + (size_t)f * M * N;
    int n0 = blockIdx.x * 32, m0 = blockIdx.y * 32;
    int tx = threadIdx.x, ty = threadIdx.y;   // block (32, 8)
#pragma unroll
    for (int i = 0; i < 32; i += 8)
        tile[ty + i][tx] = s[(size_t)(m0 + ty + i) * N + n0 + tx];
    __syncthreads();
#pragma unroll
    for (int i = 0; i < 32; i += 8)
        d[(size_t)(n0 + ty + i) * M + m0 + tx] = tile[tx][ty + i];
}

extern "C" void kernel_launch(void* const* d_in, const int* in_sizes, int n_in,
                              void* d_out, int out_size, void* d_ws, size_t ws_size,
                              hipStream_t stream) {
    const float* input = (const float*)d_in[0];
    const float* w1    = (const float*)d_in[1];
    const float* b1    = (const float*)d_in[2];
    const float* w2    = (const float*)d_in[3];
    const float* b2    = (const float*)d_in[4];
    const int*   ind0  = (const int*)d_in[5];
    const int*   ind1  = (const int*)d_in[6];
    const int*   ind2  = (const int*)d_in[7];
    const int*   mix   = (const int*)d_in[8];

    char* ws = (char*)d_ws;
    unsigned short* inT2 = (unsigned short*)ws;                   // 16 MiB
    unsigned int*   outT = (unsigned int*)(ws + (16ull << 20));   // 32 MiB
    unsigned short* w1bf = (unsigned short*)(ws + (48ull << 20)); // 4 KiB
    unsigned short* w2bf = (unsigned short*)(ws + (48ull << 20) + 4096);   // 2 KiB
    int* inv = (int*)(ws + (48ull << 20) + 8192);                 // 144 KiB
    int* g   = (int*)(ws + (48ull << 20) + 8192 + 147456);        // 144 KiB
    int* h   = (int*)(ws + (48ull << 20) + 8192 + 2 * 147456);    // 144 KiB

    int n4 = (F_OUTD * RDIM * CDIM) / 4;
    zero_kernel<<<(n4 + 255) / 256, 256, 0, stream>>>((float4*)outT, n4);

    prep_in<<<dim3(CDIM / 32, RDIM / 32), 256, 0, stream>>>(input, inT2);
    prep_w<<<1, 256, 0, stream>>>(w1, w2, w1bf, w2bf);
    build_inv<<<dim3(NIND / 256, 9), 256, 0, stream>>>(ind0, ind1, ind2, inv);
    build_gh<<<dim3(MDIM / 256, 9), 256, 0, stream>>>(ind0, ind1, ind2, mix, inv, g, h);

    mlp_mfma<<<NSETS * MDIM / 4, 256, 0, stream>>>(inT2, w1bf, w2bf, b1, b2, g, h, outT);

    dim3 tb(32, 8);
    transpose_f<<<dim3(RDIM / 32, CDIM / 32, F_OUTD), tb, 0, stream>>>(
        (const float*)outT, (float*)d_out, CDIM, RDIM);
}

// Round 4
// 119.731 us; speedup vs baseline: 2.7032x; 2.0342x over previous
//
#include <hip/hip_runtime.h>
#include <cstdint>

#define F_IN   8
#define HID    64
#define F_OUTD 8
#define RDIM   256
#define CDIM   4096
#define NSETS  3
#define NIND   4096
#define MDIM   4096
#define CAP    16

using short8 = __attribute__((ext_vector_type(8))) short;
using f32x4  = __attribute__((ext_vector_type(4))) float;

__device__ inline unsigned short f2bf(float x) {
    union { float f; unsigned int u; } v; v.f = x;
    unsigned int r = v.u + 0x7fffu + ((v.u >> 16) & 1u);   // RNE
    return (unsigned short)(r >> 16);
}
__device__ inline unsigned int packbf(float a, float b) {
    return (unsigned int)f2bf(a) | ((unsigned int)f2bf(b) << 16);
}

// ---------------- zero fill ----------------
__global__ void zero_kernel(float4* __restrict__ p, int n4) {
    int i = blockIdx.x * blockDim.x + threadIdx.x;
    if (i < n4) p[i] = make_float4(0.f, 0.f, 0.f, 0.f);
}

// ---------------- input prep: in [F][R][C] f32 -> inT2 [C][R][F] bf16 ----------
__global__ __launch_bounds__(256)
void prep_in(const float* __restrict__ in, unsigned short* __restrict__ out) {
    const int PADH = 264;                       // halfs per c-row (528B)
    __shared__ unsigned short tile[32 * PADH];
    int c0 = blockIdx.x * 32, r0 = blockIdx.y * 32;
    int t = threadIdx.x;
    int tx = t & 31, ty = t >> 5;
#pragma unroll
    for (int f = 0; f < 8; f++)
#pragma unroll
        for (int rr = 0; rr < 4; rr++) {
            int r = ty + rr * 8;
            float v = in[((size_t)f * RDIM + (r0 + r)) * CDIM + c0 + tx];
            tile[tx * PADH + r * 8 + f] = f2bf(v);
        }
    __syncthreads();
    int r = t & 31, cl = t >> 5;
#pragma unroll
    for (int cc = 0; cc < 4; cc++) {
        int c = cc * 8 + cl;
        uint4 v = *(const uint4*)&tile[c * PADH + r * 8];
        *(uint4*)(out + (((size_t)(c0 + c) * RDIM) + (r0 + r)) * 8) = v;
    }
}

// ---------------- weight prep: bf16, padded, MFMA-fragment-friendly ----------
__global__ void prep_w(const float* __restrict__ w1, const float* __restrict__ w2,
                       unsigned short* __restrict__ w1bf, unsigned short* __restrict__ w2bf) {
    int t = threadIdx.x;
    for (int i = t; i < 64 * 32; i += 256) {
        int j = i >> 5, k = i & 31;
        w1bf[i] = (k < 24) ? f2bf(w1[j * 24 + k]) : 0;
    }
    for (int i = t; i < 16 * 64; i += 256) {
        int f = i >> 6, j = i & 63;
        w2bf[i] = (f < 8) ? f2bf(w2[f * 64 + j]) : 0;
    }
}

// ---------------- build inverse permutations of col0 ----------------
__global__ void build_inv(const int* __restrict__ ind0, const int* __restrict__ ind1,
                          const int* __restrict__ ind2, int* __restrict__ inv) {
    int k  = blockIdx.x * 256 + threadIdx.x;
    int si = blockIdx.y;
    int s_ = si / 3, i_ = si % 3;
    const int* ind = (i_ == 0 ? ind0 : (i_ == 1 ? ind1 : ind2)) + (size_t)s_ * NIND * 2;
    int c0 = ind[2 * k];
    inv[(size_t)si * NIND + c0] = k;
}

// ---------------- bucket-invert the scatter: per dest col c, list of m ------
__global__ void build_buckets(const int* __restrict__ ind0, const int* __restrict__ ind1,
                              const int* __restrict__ ind2, const int* __restrict__ mix,
                              int* __restrict__ cnt, int* __restrict__ list) {
    int m  = blockIdx.x * 256 + threadIdx.x;
    int si = blockIdx.y;
    int s_ = si / 3, i_ = si % 3;
    const int* ind = (i_ == 0 ? ind0 : (i_ == 1 ? ind1 : ind2)) + (size_t)s_ * NIND * 2;
    int mi = mix[(size_t)si * MDIM + m];
    int c  = ind[2 * mi + 1];
    int slot = atomicAdd(&cnt[si * CDIM + c], 1);
    if (slot < CAP) list[((size_t)si * CDIM + c) * CAP + slot] = m;
}

// ---------------- MFMA MLP -> dense d[sloc][m][r][f] bf16 (clamped at 0) -----
__global__ __launch_bounds__(256)
void mlp_store(const unsigned short* __restrict__ inT2,
               const unsigned short* __restrict__ w1bf,
               const unsigned short* __restrict__ w2bf,
               const float* __restrict__ b1, const float* __restrict__ b2,
               const int* __restrict__ ind0, const int* __restrict__ ind1,
               const int* __restrict__ ind2, const int* __restrict__ mix,
               const int* __restrict__ inv,
               unsigned short* __restrict__ dbuf, int s_base) {
    __shared__ unsigned short lds_all[4][1024];   // 2KB per wave, barrier-free
    int t    = threadIdx.x;
    int wave = t >> 6, lane = t & 63;
    int lo = lane & 15, q = lane >> 4;

    int w_id = blockIdx.x * 4 + wave;
    int sloc = w_id >> 12;
    int m    = w_id & 4095;
    int s_   = s_base + sloc;

    short8 A1[4], A2[2];
#pragma unroll
    for (int tt = 0; tt < 4; tt++)
        A1[tt] = *(const short8*)(w1bf + ((16 * tt + lo) << 5) + (q << 3));
#pragma unroll
    for (int kk = 0; kk < 2; kk++)
        A2[kk] = *(const short8*)(w2bf + (lo << 6) + (kk << 5) + (q << 3));

    float bb[16];
#pragma unroll
    for (int tt = 0; tt < 4; tt++)
#pragma unroll
        for (int rg = 0; rg < 4; rg++)
            bb[tt * 4 + rg] = b1[16 * tt + 4 * q + rg];
    float b2v[4];
#pragma unroll
    for (int rg = 0; rg < 4; rg++) {
        int f = 4 * q + rg;
        b2v[rg] = (f < 8) ? b2[f] : 0.f;
    }

    // on-the-fly source column: g = col1[ inv[ mix ] ]
    int gq = 0;
    if (q < 3) {
        int si = s_ * 3 + q;
        int mi = mix[(size_t)si * MDIM + m];
        int k  = inv[(size_t)si * NIND + mi];
        const int* indq = (q == 0 ? ind0 : (q == 1 ? ind1 : ind2)) + (size_t)s_ * NIND * 2;
        gq = indq[2 * k + 1];
    }

    const unsigned short* src = inT2 + ((size_t)gq * RDIM + lo) * 8;
    char* lds = (char*)lds_all[wave];
    unsigned int swz   = (unsigned int)((lo & 7) << 4);
    unsigned int wbase = (unsigned int)(lo * 128 + q * 8);
    unsigned int rbase = (unsigned int)(lo * 128 + q * 16);
    unsigned short* dst = dbuf + ((size_t)sloc * MDIM + m) * (RDIM * 8);

    for (int rt = 0; rt < 16; rt++) {
        short8 B1v = {0, 0, 0, 0, 0, 0, 0, 0};
        if (q < 3) B1v = *(const short8*)(src + rt * 128);

        f32x4 acc[4];
#pragma unroll
        for (int tt = 0; tt < 4; tt++) {
            acc[tt][0] = bb[tt * 4 + 0]; acc[tt][1] = bb[tt * 4 + 1];
            acc[tt][2] = bb[tt * 4 + 2]; acc[tt][3] = bb[tt * 4 + 3];
        }
#pragma unroll
        for (int tt = 0; tt < 4; tt++)
            acc[tt] = __builtin_amdgcn_mfma_f32_16x16x32_bf16(A1[tt], B1v, acc[tt], 0, 0, 0);

#pragma unroll
        for (int tt = 0; tt < 4; tt++) {
            float v0 = fmaxf(acc[tt][0], 0.f), v1 = fmaxf(acc[tt][1], 0.f);
            float v2 = fmaxf(acc[tt][2], 0.f), v3 = fmaxf(acc[tt][3], 0.f);
            uint2 dv; dv.x = packbf(v0, v1); dv.y = packbf(v2, v3);
            *(uint2*)(lds + ((wbase + 32 * tt) ^ swz)) = dv;
        }

        short8 B2a = *(const short8*)(lds + (rbase ^ swz));
        short8 B2b = *(const short8*)(lds + ((rbase + 64) ^ swz));

        f32x4 acc2;
#pragma unroll
        for (int rg = 0; rg < 4; rg++) acc2[rg] = b2v[rg];
        acc2 = __builtin_amdgcn_mfma_f32_16x16x32_bf16(A2[0], B2a, acc2, 0, 0, 0);
        acc2 = __builtin_amdgcn_mfma_f32_16x16x32_bf16(A2[1], B2b, acc2, 0, 0, 0);

        // store d (clamped at 0; negatives never beat the zeros baseline)
        if (q < 2) {
            float v0 = fmaxf(acc2[0], 0.f), v1 = fmaxf(acc2[1], 0.f);
            float v2 = fmaxf(acc2[2], 0.f), v3 = fmaxf(acc2[3], 0.f);
            uint2 dv; dv.x = packbf(v0, v1); dv.y = packbf(v2, v3);
            *(uint2*)(dst + (size_t)(rt * 16 + lo) * 8 + q * 4) = dv;
        }
    }
}

// ---------------- gather-max per dest column -> outp [f][c][r] ----------------
__global__ __launch_bounds__(256)
void gather_max(const unsigned short* __restrict__ dbuf, const int* __restrict__ cnt,
                const int* __restrict__ list, float* __restrict__ outp,
                int si_lo, int nsi, int init) {
    int c = blockIdx.x, r = threadIdx.x;
    float of[8];
    if (init) {
#pragma unroll
        for (int f = 0; f < 8; f++) of[f] = 0.f;
    } else {
#pragma unroll
        for (int f = 0; f < 8; f++) of[f] = outp[((size_t)f * CDIM + c) * RDIM + r];
    }
    for (int ii = 0; ii < nsi; ii++) {
        int si = si_lo + ii;
        int sloc = ii / 3;     // roomy: si/3; compact (nsi=3): 0
        int n = cnt[si * CDIM + c];
        if (n > CAP) n = CAP;
        const int* lp = list + ((size_t)si * CDIM + c) * CAP;
        for (int k = 0; k < n; k++) {
            int m = lp[k];
            uint4 v = *(const uint4*)(dbuf + (((size_t)sloc * MDIM + m) * RDIM + r) * 8);
            of[0] = fmaxf(of[0], __uint_as_float(v.x << 16));
            of[1] = fmaxf(of[1], __uint_as_float(v.x & 0xffff0000u));
            of[2] = fmaxf(of[2], __uint_as_float(v.y << 16));
            of[3] = fmaxf(of[3], __uint_as_float(v.y & 0xffff0000u));
            of[4] = fmaxf(of[4], __uint_as_float(v.z << 16));
            of[5] = fmaxf(of[5], __uint_as_float(v.z & 0xffff0000u));
            of[6] = fmaxf(of[6], __uint_as_float(v.w << 16));
            of[7] = fmaxf(of[7], __uint_as_float(v.w & 0xffff0000u));
        }
    }
#pragma unroll
    for (int f = 0; f < 8; f++)
        outp[((size_t)f * CDIM + c) * RDIM + r] = of[f];
}

// ---------------- batched tiled transpose: src [F][M][N] -> dst [F][N][M] ----
__global__ void transpose_f(const float* __restrict__ src, float* __restrict__ dst,
                            int M, int N) {
    __shared__ float tile[32][33];
    int f = blockIdx.z;
    const float* s = src + (size_t)f * M * N;
    float*       d = dst + (size_t)f * M * N;
    int n0 = blockIdx.x * 32, m0 = blockIdx.y * 32;
    int tx = threadIdx.x, ty = threadIdx.y;
#pragma unroll
    for (int i = 0; i < 32; i += 8)
        tile[ty + i][tx] = s[(size_t)(m0 + ty + i) * N + n0 + tx];
    __syncthreads();
#pragma unroll
    for (int i = 0; i < 32; i += 8)
        d[(size_t)(n0 + ty + i) * M + m0 + tx] = tile[tx][ty + i];
}

extern "C" void kernel_launch(void* const* d_in, const int* in_sizes, int n_in,
                              void* d_out, int out_size, void* d_ws, size_t ws_size,
                              hipStream_t stream) {
    const float* input = (const float*)d_in[0];
    const float* w1    = (const float*)d_in[1];
    const float* b1    = (const float*)d_in[2];
    const float* w2    = (const float*)d_in[3];
    const float* b2    = (const float*)d_in[4];
    const int*   ind0  = (const int*)d_in[5];
    const int*   ind1  = (const int*)d_in[6];
    const int*   ind2  = (const int*)d_in[7];
    const int*   mix   = (const int*)d_in[8];

    const size_t MiB = 1ull << 20;
    char* ws = (char*)d_ws;

    // roomy: inT2 16Mi | d 48Mi | outT 32Mi | tables.  compact: inT2 16Mi | d 16Mi | tables.
    size_t tbl_bytes = 2ull * 147456 + 9ull * CDIM * CAP * 4 + 4096 + 2048;
    bool roomy = ws_size >= 96 * MiB + tbl_bytes;

    unsigned short* inT2 = (unsigned short*)ws;
    unsigned short* dbuf = (unsigned short*)(ws + 16 * MiB);
    float* outT;
    char*  tail;
    if (roomy) { outT = (float*)(ws + 64 * MiB); tail = ws + 96 * MiB; }
    else       { outT = (float*)d_out;           tail = ws + 32 * MiB; }

    int* inv  = (int*)tail;
    int* cnt  = (int*)(tail + 147456);
    int* list = (int*)(tail + 2 * 147456);
    unsigned short* w1bf = (unsigned short*)(tail + 2 * 147456 + 9ull * CDIM * CAP * 4);
    unsigned short* w2bf = w1bf + 64 * 32;

    prep_in<<<dim3(CDIM / 32, RDIM / 32), 256, 0, stream>>>(input, inT2);
    prep_w<<<1, 256, 0, stream>>>(w1, w2, w1bf, w2bf);
    build_inv<<<dim3(NIND / 256, 9), 256, 0, stream>>>(ind0, ind1, ind2, inv);
    zero_kernel<<<36, 256, 0, stream>>>((float4*)cnt, 9216);   // 9*4096 ints
    build_buckets<<<dim3(MDIM / 256, 9), 256, 0, stream>>>(ind0, ind1, ind2, mix, cnt, list);

    dim3 tb(32, 8);
    if (roomy) {
        mlp_store<<<NSETS * MDIM / 4, 256, 0, stream>>>(inT2, w1bf, w2bf, b1, b2,
                                                        ind0, ind1, ind2, mix, inv, dbuf, 0);
        gather_max<<<CDIM, 256, 0, stream>>>(dbuf, cnt, list, outT, 0, 9, 1);
        transpose_f<<<dim3(RDIM / 32, CDIM / 32, F_OUTD), tb, 0, stream>>>(
            outT, (float*)d_out, CDIM, RDIM);
    } else {
        for (int s = 0; s < NSETS; s++) {
            mlp_store<<<MDIM / 4, 256, 0, stream>>>(inT2, w1bf, w2bf, b1, b2,
                                                    ind0, ind1, ind2, mix, inv, dbuf, s);
            gather_max<<<CDIM, 256, 0, stream>>>(dbuf, cnt, list, outT, 3 * s, 3, s == 0);
        }
        float* tmp = (float*)ws;   // inT2 + dbuf are dead now; 32Mi available
        transpose_f<<<dim3(RDIM / 32, CDIM / 32, F_OUTD), tb, 0, stream>>>(
            outT, tmp, CDIM, RDIM);
        hipMemcpyAsync(d_out, tmp, 32 * MiB, hipMemcpyDeviceToDevice, stream);
    }
}

// Round 5
// 109.615 us; speedup vs baseline: 2.9527x; 1.0923x over previous
//
#include <hip/hip_runtime.h>
#include <cstdint>

#define F_IN   8
#define HID    64
#define F_OUTD 8
#define RDIM   256
#define CDIM   4096
#define NSETS  3
#define NIND   4096
#define MDIM   4096
#define CAP    16
#define MAXL   48
#define GC     16

using short8 = __attribute__((ext_vector_type(8))) short;
using f32x4  = __attribute__((ext_vector_type(4))) float;

// hardware packed f32->bf16 (RNE), low word = a
__device__ inline unsigned int cvtpk(float a, float b) {
    unsigned int r;
    asm("v_cvt_pk_bf16_f32 %0, %1, %2" : "=v"(r) : "v"(a), "v"(b));
    return r;
}

// ---------------- input prep: in [F][R][C] f32 -> inT2 [C][R][F] bf16 ----------
__global__ __launch_bounds__(256)
void prep_in(const float* __restrict__ in, unsigned short* __restrict__ out) {
    const int PADH = 264;                       // halfs per c-row (528B)
    __shared__ unsigned short tile[32 * PADH];
    int c0 = blockIdx.x * 32, r0 = blockIdx.y * 32;
    int t = threadIdx.x;
    int tx = t & 31, ty = t >> 5;
#pragma unroll
    for (int f = 0; f < 8; f += 2)
#pragma unroll
        for (int rr = 0; rr < 4; rr++) {
            int r = ty + rr * 8;
            float v0 = in[((size_t)f * RDIM + (r0 + r)) * CDIM + c0 + tx];
            float v1 = in[((size_t)(f + 1) * RDIM + (r0 + r)) * CDIM + c0 + tx];
            *(unsigned int*)&tile[tx * PADH + r * 8 + f] = cvtpk(v0, v1);
        }
    __syncthreads();
    int r = t & 31, cl = t >> 5;
#pragma unroll
    for (int cc = 0; cc < 4; cc++) {
        int c = cc * 8 + cl;
        uint4 v = *(const uint4*)&tile[c * PADH + r * 8];
        *(uint4*)(out + (((size_t)(c0 + c) * RDIM) + (r0 + r)) * 8) = v;
    }
}

// ---------------- setup: inverse perms + cnt zero + weight prep ----------------
// grid (16, 9), 256 thr. inv[si][c0]=k s.t. ind_i[s][k][0]==c0; cnt zeroed;
// block (0,0) additionally converts weights to padded bf16.
__global__ void build_inv(const int* __restrict__ ind0, const int* __restrict__ ind1,
                          const int* __restrict__ ind2,
                          const float* __restrict__ w1, const float* __restrict__ w2,
                          int* __restrict__ inv, int* __restrict__ cnt,
                          unsigned short* __restrict__ w1bf, unsigned short* __restrict__ w2bf) {
    int k  = blockIdx.x * 256 + threadIdx.x;
    int si = blockIdx.y;
    int s_ = si / 3, i_ = si % 3;
    const int* ind = (i_ == 0 ? ind0 : (i_ == 1 ? ind1 : ind2)) + (size_t)s_ * NIND * 2;
    int c0 = ind[2 * k];
    inv[(size_t)si * NIND + c0] = k;
    cnt[si * CDIM + k] = 0;
    if (blockIdx.x == 0 && blockIdx.y == 0) {
        int t = threadIdx.x;
        for (int i = t; i < 64 * 32; i += 256) {
            int j = i >> 5, kk = i & 31;
            w1bf[i] = (kk < 24) ? (unsigned short)(cvtpk(w1[j * 24 + kk], 0.f) & 0xffff) : 0;
        }
        for (int i = t; i < 16 * 64; i += 256) {
            int f = i >> 6, j = i & 63;
            w2bf[i] = (f < 8) ? (unsigned short)(cvtpk(w2[f * 64 + j], 0.f) & 0xffff) : 0;
        }
    }
}

// ---------------- bucket-invert the scatter: per dest col c, list of m ------
__global__ void build_buckets(const int* __restrict__ ind0, const int* __restrict__ ind1,
                              const int* __restrict__ ind2, const int* __restrict__ mix,
                              int* __restrict__ cnt, int* __restrict__ list) {
    int m  = blockIdx.x * 256 + threadIdx.x;
    int si = blockIdx.y;
    int s_ = si / 3, i_ = si % 3;
    const int* ind = (i_ == 0 ? ind0 : (i_ == 1 ? ind1 : ind2)) + (size_t)s_ * NIND * 2;
    int mi = mix[(size_t)si * MDIM + m];
    int c  = ind[2 * mi + 1];
    int slot = atomicAdd(&cnt[si * CDIM + c], 1);
    if (slot < CAP) list[((size_t)si * CDIM + c) * CAP + slot] = m;
}

// ---------------- MFMA MLP -> dense d[s*M+m][r][f] bf16 (clamped at 0) -----
// One wave per (s,m). LDS row stride 144B: write b64 banks (36lo+8tt+2q)%32
// uniform 4/bank (optimal), read b128 (36lo+4q)%32 uniform 8/bank (optimal).
__global__ __launch_bounds__(256)
void mlp_store(const unsigned short* __restrict__ inT2,
               const unsigned short* __restrict__ w1bf,
               const unsigned short* __restrict__ w2bf,
               const float* __restrict__ b1, const float* __restrict__ b2,
               const int* __restrict__ ind0, const int* __restrict__ ind1,
               const int* __restrict__ ind2, const int* __restrict__ mix,
               const int* __restrict__ inv,
               unsigned short* __restrict__ dbuf) {
    __shared__ char lds_all[4][2304];   // 16 rows x 144B per wave, barrier-free
    int t    = threadIdx.x;
    int wave = t >> 6, lane = t & 63;
    int lo = lane & 15, q = lane >> 4;

    int w_id = blockIdx.x * 4 + wave;   // = s*MDIM + m
    int s_   = w_id >> 12;
    int m    = w_id & 4095;

    short8 A1[4], A2[2];
#pragma unroll
    for (int tt = 0; tt < 4; tt++)
        A1[tt] = *(const short8*)(w1bf + ((16 * tt + lo) << 5) + (q << 3));
#pragma unroll
    for (int kk = 0; kk < 2; kk++)
        A2[kk] = *(const short8*)(w2bf + (lo << 6) + (kk << 5) + (q << 3));

    // biases as MFMA C-operand fragments (no per-iter mov)
    f32x4 bbv[4];
#pragma unroll
    for (int tt = 0; tt < 4; tt++)
#pragma unroll
        for (int rg = 0; rg < 4; rg++)
            bbv[tt][rg] = b1[16 * tt + 4 * q + rg];
    f32x4 b2f;
#pragma unroll
    for (int rg = 0; rg < 4; rg++) {
        int f = 4 * q + rg;
        b2f[rg] = (f < 8) ? b2[f] : 0.f;
    }

    // source column g = col1[ inv[ mix ] ]; q==3 lanes read a zero row of w2bf
    const unsigned short* src;
    int sstep;
    if (q < 3) {
        int si = s_ * 3 + q;
        int mi = mix[(size_t)si * MDIM + m];
        int k  = inv[(size_t)si * NIND + mi];
        const int* indq = (q == 0 ? ind0 : (q == 1 ? ind1 : ind2)) + (size_t)s_ * NIND * 2;
        int gq = indq[2 * k + 1];
        src = inT2 + ((size_t)gq * RDIM + lo) * 8;
        sstep = 128;
    } else {
        src = w2bf + (8 << 6);   // f>=8 rows are zero
        sstep = 0;
    }

    char* lds = lds_all[wave];
    char* lw  = lds + lo * 144 + q * 8;    // write base (+32*tt)
    char* lr  = lds + lo * 144 + q * 16;   // read base (+0 / +64)
    unsigned short* dst = dbuf + ((size_t)w_id) * (RDIM * 8) + lo * 8 + q * 4;

    for (int rt = 0; rt < 16; rt++) {
        short8 B1v = *(const short8*)src; src += sstep;

        f32x4 a0 = __builtin_amdgcn_mfma_f32_16x16x32_bf16(A1[0], B1v, bbv[0], 0, 0, 0);
        f32x4 a1 = __builtin_amdgcn_mfma_f32_16x16x32_bf16(A1[1], B1v, bbv[1], 0, 0, 0);
        f32x4 a2 = __builtin_amdgcn_mfma_f32_16x16x32_bf16(A1[2], B1v, bbv[2], 0, 0, 0);
        f32x4 a3 = __builtin_amdgcn_mfma_f32_16x16x32_bf16(A1[3], B1v, bbv[3], 0, 0, 0);

        uint2 dv;
        dv.x = cvtpk(fmaxf(a0[0], 0.f), fmaxf(a0[1], 0.f));
        dv.y = cvtpk(fmaxf(a0[2], 0.f), fmaxf(a0[3], 0.f));
        *(uint2*)(lw +  0) = dv;
        dv.x = cvtpk(fmaxf(a1[0], 0.f), fmaxf(a1[1], 0.f));
        dv.y = cvtpk(fmaxf(a1[2], 0.f), fmaxf(a1[3], 0.f));
        *(uint2*)(lw + 32) = dv;
        dv.x = cvtpk(fmaxf(a2[0], 0.f), fmaxf(a2[1], 0.f));
        dv.y = cvtpk(fmaxf(a2[2], 0.f), fmaxf(a2[3], 0.f));
        *(uint2*)(lw + 64) = dv;
        dv.x = cvtpk(fmaxf(a3[0], 0.f), fmaxf(a3[1], 0.f));
        dv.y = cvtpk(fmaxf(a3[2], 0.f), fmaxf(a3[3], 0.f));
        *(uint2*)(lw + 96) = dv;

        short8 B2a = *(const short8*)(lr);
        short8 B2b = *(const short8*)(lr + 64);

        f32x4 o = __builtin_amdgcn_mfma_f32_16x16x32_bf16(A2[0], B2a, b2f, 0, 0, 0);
        o = __builtin_amdgcn_mfma_f32_16x16x32_bf16(A2[1], B2b, o, 0, 0, 0);

        if (q < 2) {
            uint2 ov;
            ov.x = cvtpk(fmaxf(o[0], 0.f), fmaxf(o[1], 0.f));
            ov.y = cvtpk(fmaxf(o[2], 0.f), fmaxf(o[3], 0.f));
            *(uint2*)(dst + (size_t)rt * 128) = ov;
        }
    }
}

// ---------------- gather-max per dest column -> d_out [f][r][c] directly ------
// grid (CDIM/GC, 4); block owns GC columns x 64 rows (4 passes of 16 r).
__global__ __launch_bounds__(256)
void gather_max_t(const unsigned short* __restrict__ dbuf, const int* __restrict__ cnt,
                  const int* __restrict__ list, float* __restrict__ out) {
    __shared__ float ldsT[8][16][20];   // [f][rloc][c] (20-pad: rows 16B-aligned)
    __shared__ int   mlist[GC][MAXL];
    __shared__ int   mcnt[GC];
    int c0 = blockIdx.x * GC;
    int t  = threadIdx.x;
    int tc = t >> 4, tr = t & 15;
    int c  = c0 + tc;

    if (tr == 0) {   // one builder thread per column: merge 9 buckets
        int n = 0;
        for (int si = 0; si < 9; si++) {
            int s = si / 3;
            int k = cnt[si * CDIM + c]; if (k > CAP) k = CAP;
            const int* lp = list + ((size_t)si * CDIM + c) * CAP;
            for (int e = 0; e < k && n < MAXL; e++)
                mlist[tc][n++] = s * MDIM + lp[e];
        }
        mcnt[tc] = n;
    }
    __syncthreads();
    int n = mcnt[tc];

    for (int p = 0; p < 4; p++) {
        int rr = blockIdx.y * 4 + p;
        int r  = rr * 16 + tr;
        float of0 = 0.f, of1 = 0.f, of2 = 0.f, of3 = 0.f,
              of4 = 0.f, of5 = 0.f, of6 = 0.f, of7 = 0.f;
        for (int e = 0; e < n; e++) {
            int idx = mlist[tc][e];
            uint4 v = *(const uint4*)(dbuf + ((size_t)idx * RDIM + r) * 8);
            of0 = fmaxf(of0, __uint_as_float(v.x << 16));
            of1 = fmaxf(of1, __uint_as_float(v.x & 0xffff0000u));
            of2 = fmaxf(of2, __uint_as_float(v.y << 16));
            of3 = fmaxf(of3, __uint_as_float(v.y & 0xffff0000u));
            of4 = fmaxf(of4, __uint_as_float(v.z << 16));
            of5 = fmaxf(of5, __uint_as_float(v.z & 0xffff0000u));
            of6 = fmaxf(of6, __uint_as_float(v.w << 16));
            of7 = fmaxf(of7, __uint_as_float(v.w & 0xffff0000u));
        }
        __syncthreads();   // previous drain done before refill
        ldsT[0][tr][tc] = of0; ldsT[1][tr][tc] = of1;
        ldsT[2][tr][tc] = of2; ldsT[3][tr][tc] = of3;
        ldsT[4][tr][tc] = of4; ldsT[5][tr][tc] = of5;
        ldsT[6][tr][tc] = of6; ldsT[7][tr][tc] = of7;
        __syncthreads();
#pragma unroll
        for (int k2 = 0; k2 < 2; k2++) {
            int idx2 = t * 2 + k2;                 // 0..511
            int f = idx2 >> 6, rl = (idx2 >> 2) & 15, cq = idx2 & 3;
            *(float4*)&out[((size_t)f * RDIM + rr * 16 + rl) * CDIM + c0 + cq * 4] =
                *(const float4*)&ldsT[f][rl][cq * 4];
        }
    }
}

extern "C" void kernel_launch(void* const* d_in, const int* in_sizes, int n_in,
                              void* d_out, int out_size, void* d_ws, size_t ws_size,
                              hipStream_t stream) {
    const float* input = (const float*)d_in[0];
    const float* w1    = (const float*)d_in[1];
    const float* b1    = (const float*)d_in[2];
    const float* w2    = (const float*)d_in[3];
    const float* b2    = (const float*)d_in[4];
    const int*   ind0  = (const int*)d_in[5];
    const int*   ind1  = (const int*)d_in[6];
    const int*   ind2  = (const int*)d_in[7];
    const int*   mix   = (const int*)d_in[8];

    const size_t MiB = 1ull << 20;
    char* ws = (char*)d_ws;
    unsigned short* inT2 = (unsigned short*)ws;                    // 16 MiB
    unsigned short* dbuf = (unsigned short*)(ws + 16 * MiB);       // 48 MiB
    char* tail = ws + 64 * MiB;
    int* inv  = (int*)tail;                                        // 144 KiB
    int* cnt  = (int*)(tail + 147456);                             // 144 KiB
    int* list = (int*)(tail + 2 * 147456);                         // 2.25 MiB
    unsigned short* w1bf = (unsigned short*)(tail + 2 * 147456 + 9ull * CDIM * CAP * 4);
    unsigned short* w2bf = w1bf + 64 * 32;

    prep_in<<<dim3(CDIM / 32, RDIM / 32), 256, 0, stream>>>(input, inT2);
    build_inv<<<dim3(NIND / 256, 9), 256, 0, stream>>>(ind0, ind1, ind2, w1, w2,
                                                       inv, cnt, w1bf, w2bf);
    build_buckets<<<dim3(MDIM / 256, 9), 256, 0, stream>>>(ind0, ind1, ind2, mix, cnt, list);
    mlp_store<<<NSETS * MDIM / 4, 256, 0, stream>>>(inT2, w1bf, w2bf, b1, b2,
                                                    ind0, ind1, ind2, mix, inv, dbuf);
    gather_max_t<<<dim3(CDIM / GC, 4), 256, 0, stream>>>(dbuf, cnt, list, (float*)d_out);
}

// Round 6
// 108.443 us; speedup vs baseline: 2.9846x; 1.0108x over previous
//
#include <hip/hip_runtime.h>
#include <cstdint>

#define F_IN   8
#define HID    64
#define F_OUTD 8
#define RDIM   256
#define CDIM   4096
#define NSETS  3
#define NIND   4096
#define MDIM   4096
#define CAP    16
#define MAXL   48
#define GC     16

using short8 = __attribute__((ext_vector_type(8))) short;
using f32x4  = __attribute__((ext_vector_type(4))) float;

// hardware packed f32->bf16 (RNE), low word = a
__device__ inline unsigned int cvtpk(float a, float b) {
    unsigned int r;
    asm("v_cvt_pk_bf16_f32 %0, %1, %2" : "=v"(r) : "v"(a), "v"(b));
    return r;
}

// ---------------- input prep: in [F][R][C] f32 -> inT2 [C][R][F] bf16 ----------
__global__ __launch_bounds__(256)
void prep_in(const float* __restrict__ in, unsigned short* __restrict__ out) {
    const int PADH = 264;                       // halfs per c-row (528B)
    __shared__ unsigned short tile[32 * PADH];
    int c0 = blockIdx.x * 32, r0 = blockIdx.y * 32;
    int t = threadIdx.x;
    int tx = t & 31, ty = t >> 5;
#pragma unroll
    for (int f = 0; f < 8; f += 2)
#pragma unroll
        for (int rr = 0; rr < 4; rr++) {
            int r = ty + rr * 8;
            float v0 = in[((size_t)f * RDIM + (r0 + r)) * CDIM + c0 + tx];
            float v1 = in[((size_t)(f + 1) * RDIM + (r0 + r)) * CDIM + c0 + tx];
            *(unsigned int*)&tile[tx * PADH + r * 8 + f] = cvtpk(v0, v1);
        }
    __syncthreads();
    int r = t & 31, cl = t >> 5;
#pragma unroll
    for (int cc = 0; cc < 4; cc++) {
        int c = cc * 8 + cl;
        uint4 v = *(const uint4*)&tile[c * PADH + r * 8];
        *(uint4*)(out + (((size_t)(c0 + c) * RDIM) + (r0 + r)) * 8) = v;
    }
}

// ---------------- setup: inverse perms + cnt zero + weight prep ----------------
// inv[si][c0]=k s.t. ind_i[s][k][0]==c0; cnt zeroed; block (0,0) converts
// weights to bf16. w2's columns are permuted by tau so that layer-1's packed
// relu output (D-fragment order) is directly the layer-2 B-fragment:
//   tau(32*hi + 8*q + e) = 32*hi + 16*(e>>2) + 4*q + (e&3)
__global__ void build_inv(const int* __restrict__ ind0, const int* __restrict__ ind1,
                          const int* __restrict__ ind2,
                          const float* __restrict__ w1, const float* __restrict__ w2,
                          int* __restrict__ inv, int* __restrict__ cnt,
                          unsigned short* __restrict__ w1bf, unsigned short* __restrict__ w2bf) {
    int k  = blockIdx.x * 256 + threadIdx.x;
    int si = blockIdx.y;
    int s_ = si / 3, i_ = si % 3;
    const int* ind = (i_ == 0 ? ind0 : (i_ == 1 ? ind1 : ind2)) + (size_t)s_ * NIND * 2;
    int c0 = ind[2 * k];
    inv[(size_t)si * NIND + c0] = k;
    cnt[si * CDIM + k] = 0;
    if (blockIdx.x == 0 && blockIdx.y == 0) {
        int t = threadIdx.x;
        for (int i = t; i < 64 * 32; i += 256) {
            int j = i >> 5, kk = i & 31;
            w1bf[i] = (kk < 24) ? (unsigned short)(cvtpk(w1[j * 24 + kk], 0.f) & 0xffff) : 0;
        }
        for (int i = t; i < 16 * 64; i += 256) {
            int f = i >> 6, kg = i & 63;
            int hi = kg >> 5, q = (kg >> 3) & 3, e = kg & 7;
            int j = (hi << 5) + ((e >> 2) << 4) + (q << 2) + (e & 3);   // tau
            w2bf[i] = (f < 8) ? (unsigned short)(cvtpk(w2[f * 64 + j], 0.f) & 0xffff) : 0;
        }
    }
}

// ---------------- bucket-invert the scatter: per dest col c, list of m ------
__global__ void build_buckets(const int* __restrict__ ind0, const int* __restrict__ ind1,
                              const int* __restrict__ ind2, const int* __restrict__ mix,
                              int* __restrict__ cnt, int* __restrict__ list) {
    int m  = blockIdx.x * 256 + threadIdx.x;
    int si = blockIdx.y;
    int s_ = si / 3, i_ = si % 3;
    const int* ind = (i_ == 0 ? ind0 : (i_ == 1 ? ind1 : ind2)) + (size_t)s_ * NIND * 2;
    int mi = mix[(size_t)si * MDIM + m];
    int c  = ind[2 * mi + 1];
    int slot = atomicAdd(&cnt[si * CDIM + c], 1);
    if (slot < CAP) list[((size_t)si * CDIM + c) * CAP + slot] = m;
}

// ---------------- MFMA MLP -> dense d[s*M+m][r][f] bf16 (clamped at 0) -----
// One wave per (s,m, half-of-r). Fully in-register: layer-1 D output, after
// relu+cvtpk, IS the layer-2 B fragment (w2 columns pre-permuted by tau).
// No LDS, no cross-lane ops; B1 prefetched one iteration ahead.
__global__ __launch_bounds__(256)
void mlp_store(const unsigned short* __restrict__ inT2,
               const unsigned short* __restrict__ w1bf,
               const unsigned short* __restrict__ w2bf,
               const float* __restrict__ b1, const float* __restrict__ b2,
               const int* __restrict__ ind0, const int* __restrict__ ind1,
               const int* __restrict__ ind2, const int* __restrict__ mix,
               const int* __restrict__ inv,
               unsigned short* __restrict__ dbuf) {
    int t    = threadIdx.x;
    int wave = t >> 6, lane = t & 63;
    int lo = lane & 15, q = lane >> 4;

    int wid2 = blockIdx.x * 4 + wave;    // 0..24575
    int half = wid2 & 1;                 // which 128-row slab
    int w_id = wid2 >> 1;                // = s*MDIM + m
    int s_   = w_id >> 12;
    int m    = w_id & 4095;

    short8 A1[4], A2[2];
#pragma unroll
    for (int tt = 0; tt < 4; tt++)
        A1[tt] = *(const short8*)(w1bf + ((16 * tt + lo) << 5) + (q << 3));
#pragma unroll
    for (int kk = 0; kk < 2; kk++)
        A2[kk] = *(const short8*)(w2bf + (lo << 6) + (kk << 5) + (q << 3));

    // biases as MFMA C-operand fragments
    f32x4 bbv[4];
#pragma unroll
    for (int tt = 0; tt < 4; tt++)
#pragma unroll
        for (int rg = 0; rg < 4; rg++)
            bbv[tt][rg] = b1[16 * tt + 4 * q + rg];
    f32x4 b2f;
#pragma unroll
    for (int rg = 0; rg < 4; rg++) {
        int f = 4 * q + rg;
        b2f[rg] = (f < 8) ? b2[f] : 0.f;
    }

    // source column g = col1[ inv[ mix ] ]; q==3 lanes read a zero row of w2bf
    const unsigned short* src;
    int sstep;
    if (q < 3) {
        int si = s_ * 3 + q;
        int mi = mix[(size_t)si * MDIM + m];
        int k  = inv[(size_t)si * NIND + mi];
        const int* indq = (q == 0 ? ind0 : (q == 1 ? ind1 : ind2)) + (size_t)s_ * NIND * 2;
        int gq = indq[2 * k + 1];
        src = inT2 + ((size_t)gq * RDIM + half * 128 + lo) * 8;
        sstep = 128;   // 16 rows * 8 halfs
    } else {
        src = w2bf + (8 << 6);   // f>=8 rows are zero (K padding)
        sstep = 0;
    }

    unsigned short* dst = dbuf + (size_t)w_id * 2048 + half * 1024 + lo * 8 + q * 4;

    union U { unsigned int u[4]; short8 s; };

    short8 Bcur = *(const short8*)src;
    for (int j = 0; j < 8; j++) {
        short8 Bnext = Bcur;
        if (j < 7) Bnext = *(const short8*)(src + (j + 1) * sstep);

        f32x4 a0 = __builtin_amdgcn_mfma_f32_16x16x32_bf16(A1[0], Bcur, bbv[0], 0, 0, 0);
        f32x4 a1 = __builtin_amdgcn_mfma_f32_16x16x32_bf16(A1[1], Bcur, bbv[1], 0, 0, 0);
        f32x4 a2 = __builtin_amdgcn_mfma_f32_16x16x32_bf16(A1[2], Bcur, bbv[2], 0, 0, 0);
        f32x4 a3 = __builtin_amdgcn_mfma_f32_16x16x32_bf16(A1[3], Bcur, bbv[3], 0, 0, 0);

        // relu + pack: result IS the layer-2 B fragment (tau-permuted w2)
        U ba, bb;
        ba.u[0] = cvtpk(fmaxf(a0[0], 0.f), fmaxf(a0[1], 0.f));
        ba.u[1] = cvtpk(fmaxf(a0[2], 0.f), fmaxf(a0[3], 0.f));
        ba.u[2] = cvtpk(fmaxf(a1[0], 0.f), fmaxf(a1[1], 0.f));
        ba.u[3] = cvtpk(fmaxf(a1[2], 0.f), fmaxf(a1[3], 0.f));
        bb.u[0] = cvtpk(fmaxf(a2[0], 0.f), fmaxf(a2[1], 0.f));
        bb.u[1] = cvtpk(fmaxf(a2[2], 0.f), fmaxf(a2[3], 0.f));
        bb.u[2] = cvtpk(fmaxf(a3[0], 0.f), fmaxf(a3[1], 0.f));
        bb.u[3] = cvtpk(fmaxf(a3[2], 0.f), fmaxf(a3[3], 0.f));

        f32x4 o = __builtin_amdgcn_mfma_f32_16x16x32_bf16(A2[0], ba.s, b2f, 0, 0, 0);
        o = __builtin_amdgcn_mfma_f32_16x16x32_bf16(A2[1], bb.s, o, 0, 0, 0);

        // store d (clamped at 0; negatives never beat the zeros baseline)
        if (q < 2) {
            uint2 ov;
            ov.x = cvtpk(fmaxf(o[0], 0.f), fmaxf(o[1], 0.f));
            ov.y = cvtpk(fmaxf(o[2], 0.f), fmaxf(o[3], 0.f));
            *(uint2*)(dst + (size_t)j * 128) = ov;
        }
        Bcur = Bnext;
    }
}

// ---------------- gather-max per dest column -> d_out [f][r][c] directly ------
// grid (CDIM/GC, 16); block owns GC columns x one 16-row slab.
__global__ __launch_bounds__(256)
void gather_max_t(const unsigned short* __restrict__ dbuf, const int* __restrict__ cnt,
                  const int* __restrict__ list, float* __restrict__ out) {
    __shared__ float ldsT[8][16][20];   // [f][rloc][c] (20-pad)
    __shared__ int   mlist[GC][MAXL];
    __shared__ int   mcnt[GC];
    int c0 = blockIdx.x * GC;
    int t  = threadIdx.x;
    int tc = t >> 4, tr = t & 15;
    int c  = c0 + tc;

    if (tr == 0) {   // one builder thread per column: merge 9 buckets
        int n = 0;
        for (int si = 0; si < 9; si++) {
            int s = si / 3;
            int k = cnt[si * CDIM + c]; if (k > CAP) k = CAP;
            const int* lp = list + ((size_t)si * CDIM + c) * CAP;
            for (int e = 0; e < k && n < MAXL; e++)
                mlist[tc][n++] = s * MDIM + lp[e];
        }
        mcnt[tc] = n;
    }
    __syncthreads();
    int n = mcnt[tc];

    int r = blockIdx.y * 16 + tr;
    float of0 = 0.f, of1 = 0.f, of2 = 0.f, of3 = 0.f,
          of4 = 0.f, of5 = 0.f, of6 = 0.f, of7 = 0.f;
    for (int e = 0; e < n; e++) {
        int idx = mlist[tc][e];
        uint4 v = *(const uint4*)(dbuf + ((size_t)idx * RDIM + r) * 8);
        of0 = fmaxf(of0, __uint_as_float(v.x << 16));
        of1 = fmaxf(of1, __uint_as_float(v.x & 0xffff0000u));
        of2 = fmaxf(of2, __uint_as_float(v.y << 16));
        of3 = fmaxf(of3, __uint_as_float(v.y & 0xffff0000u));
        of4 = fmaxf(of4, __uint_as_float(v.z << 16));
        of5 = fmaxf(of5, __uint_as_float(v.z & 0xffff0000u));
        of6 = fmaxf(of6, __uint_as_float(v.w << 16));
        of7 = fmaxf(of7, __uint_as_float(v.w & 0xffff0000u));
    }
    ldsT[0][tr][tc] = of0; ldsT[1][tr][tc] = of1;
    ldsT[2][tr][tc] = of2; ldsT[3][tr][tc] = of3;
    ldsT[4][tr][tc] = of4; ldsT[5][tr][tc] = of5;
    ldsT[6][tr][tc] = of6; ldsT[7][tr][tc] = of7;
    __syncthreads();
#pragma unroll
    for (int k2 = 0; k2 < 2; k2++) {
        int idx2 = t * 2 + k2;                 // 0..511
        int f = idx2 >> 6, rl = (idx2 >> 2) & 15, cq = idx2 & 3;
        *(float4*)&out[((size_t)f * RDIM + blockIdx.y * 16 + rl) * CDIM + c0 + cq * 4] =
            *(const float4*)&ldsT[f][rl][cq * 4];
    }
}

extern "C" void kernel_launch(void* const* d_in, const int* in_sizes, int n_in,
                              void* d_out, int out_size, void* d_ws, size_t ws_size,
                              hipStream_t stream) {
    const float* input = (const float*)d_in[0];
    const float* w1    = (const float*)d_in[1];
    const float* b1    = (const float*)d_in[2];
    const float* w2    = (const float*)d_in[3];
    const float* b2    = (const float*)d_in[4];
    const int*   ind0  = (const int*)d_in[5];
    const int*   ind1  = (const int*)d_in[6];
    const int*   ind2  = (const int*)d_in[7];
    const int*   mix   = (const int*)d_in[8];

    const size_t MiB = 1ull << 20;
    char* ws = (char*)d_ws;
    unsigned short* inT2 = (unsigned short*)ws;                    // 16 MiB
    unsigned short* dbuf = (unsigned short*)(ws + 16 * MiB);       // 48 MiB
    char* tail = ws + 64 * MiB;
    int* inv  = (int*)tail;                                        // 144 KiB
    int* cnt  = (int*)(tail + 147456);                             // 144 KiB
    int* list = (int*)(tail + 2 * 147456);                         // 2.25 MiB
    unsigned short* w1bf = (unsigned short*)(tail + 2 * 147456 + 9ull * CDIM * CAP * 4);
    unsigned short* w2bf = w1bf + 64 * 32;

    prep_in<<<dim3(CDIM / 32, RDIM / 32), 256, 0, stream>>>(input, inT2);
    build_inv<<<dim3(NIND / 256, 9), 256, 0, stream>>>(ind0, ind1, ind2, w1, w2,
                                                       inv, cnt, w1bf, w2bf);
    build_buckets<<<dim3(MDIM / 256, 9), 256, 0, stream>>>(ind0, ind1, ind2, mix, cnt, list);
    mlp_store<<<NSETS * MDIM / 2, 256, 0, stream>>>(inT2, w1bf, w2bf, b1, b2,
                                                    ind0, ind1, ind2, mix, inv, dbuf);
    gather_max_t<<<dim3(CDIM / GC, 16), 256, 0, stream>>>(dbuf, cnt, list, (float*)d_out);
}

// Round 7
// 94.043 us; speedup vs baseline: 3.4416x; 1.1531x over previous
//
#include <hip/hip_runtime.h>
#include <cstdint>

#define F_IN   8
#define HID    64
#define F_OUTD 8
#define RDIM   256
#define CDIM   4096
#define NSETS  3
#define NIND   4096
#define MDIM   4096
#define CAP    16
#define MAXL   48
#define GC     16
#define MPW    4

using short8 = __attribute__((ext_vector_type(8))) short;
using f32x4  = __attribute__((ext_vector_type(4))) float;

// hardware packed f32->bf16 (RNE), low word = a
__device__ inline unsigned int cvtpk(float a, float b) {
    unsigned int r;
    asm("v_cvt_pk_bf16_f32 %0, %1, %2" : "=v"(r) : "v"(a), "v"(b));
    return r;
}
// packed unsigned 16-bit max (== bf16 max for nonnegative values)
__device__ inline unsigned int pkmaxu(unsigned int a, unsigned int b) {
    unsigned int r;
    asm("v_pk_max_u16 %0, %1, %2" : "=v"(r) : "v"(a), "v"(b));
    return r;
}

// ---------------- input prep: in [F][R][C] f32 -> inT2 [C][R][F] bf16 ----------
__global__ __launch_bounds__(256)
void prep_in(const float* __restrict__ in, unsigned short* __restrict__ out) {
    const int PADH = 264;                       // halfs per c-row (528B)
    __shared__ unsigned short tile[32 * PADH];
    int c0 = blockIdx.x * 32, r0 = blockIdx.y * 32;
    int t = threadIdx.x;
    int tx = t & 31, ty = t >> 5;
#pragma unroll
    for (int f = 0; f < 8; f += 2)
#pragma unroll
        for (int rr = 0; rr < 4; rr++) {
            int r = ty + rr * 8;
            float v0 = in[((size_t)f * RDIM + (r0 + r)) * CDIM + c0 + tx];
            float v1 = in[((size_t)(f + 1) * RDIM + (r0 + r)) * CDIM + c0 + tx];
            *(unsigned int*)&tile[tx * PADH + r * 8 + f] = cvtpk(v0, v1);
        }
    __syncthreads();
    int r = t & 31, cl = t >> 5;
#pragma unroll
    for (int cc = 0; cc < 4; cc++) {
        int c = cc * 8 + cl;
        uint4 v = *(const uint4*)&tile[c * PADH + r * 8];
        *(uint4*)(out + (((size_t)(c0 + c) * RDIM) + (r0 + r)) * 8) = v;
    }
}

// ---------------- setup: inverse perms + cnt zero + weight prep ----------------
// inv[si][c0]=k s.t. ind_i[s][k][0]==c0; cnt zeroed; block (0,0) converts
// weights to bf16. w2's columns are permuted by tau so that layer-1's packed
// relu output (D-fragment order) is directly the layer-2 B-fragment:
//   tau(32*hi + 8*q + e) = 32*hi + 16*(e>>2) + 4*q + (e&3)
__global__ void build_inv(const int* __restrict__ ind0, const int* __restrict__ ind1,
                          const int* __restrict__ ind2,
                          const float* __restrict__ w1, const float* __restrict__ w2,
                          int* __restrict__ inv, int* __restrict__ cnt,
                          unsigned short* __restrict__ w1bf, unsigned short* __restrict__ w2bf) {
    int k  = blockIdx.x * 256 + threadIdx.x;
    int si = blockIdx.y;
    int s_ = si / 3, i_ = si % 3;
    const int* ind = (i_ == 0 ? ind0 : (i_ == 1 ? ind1 : ind2)) + (size_t)s_ * NIND * 2;
    int c0 = ind[2 * k];
    inv[(size_t)si * NIND + c0] = k;
    cnt[si * CDIM + k] = 0;
    if (blockIdx.x == 0 && blockIdx.y == 0) {
        int t = threadIdx.x;
        for (int i = t; i < 64 * 32; i += 256) {
            int j = i >> 5, kk = i & 31;
            w1bf[i] = (kk < 24) ? (unsigned short)(cvtpk(w1[j * 24 + kk], 0.f) & 0xffff) : 0;
        }
        for (int i = t; i < 16 * 64; i += 256) {
            int f = i >> 6, kg = i & 63;
            int hi = kg >> 5, q = (kg >> 3) & 3, e = kg & 7;
            int j = (hi << 5) + ((e >> 2) << 4) + (q << 2) + (e & 3);   // tau
            w2bf[i] = (f < 8) ? (unsigned short)(cvtpk(w2[f * 64 + j], 0.f) & 0xffff) : 0;
        }
    }
}

// ---------------- bucket-invert the scatter: per dest col c, list of m ------
__global__ void build_buckets(const int* __restrict__ ind0, const int* __restrict__ ind1,
                              const int* __restrict__ ind2, const int* __restrict__ mix,
                              int* __restrict__ cnt, int* __restrict__ list) {
    int m  = blockIdx.x * 256 + threadIdx.x;
    int si = blockIdx.y;
    int s_ = si / 3, i_ = si % 3;
    const int* ind = (i_ == 0 ? ind0 : (i_ == 1 ? ind1 : ind2)) + (size_t)s_ * NIND * 2;
    int mi = mix[(size_t)si * MDIM + m];
    int c  = ind[2 * mi + 1];
    int slot = atomicAdd(&cnt[si * CDIM + c], 1);
    if (slot < CAP) list[((size_t)si * CDIM + c) * CAP + slot] = m;
}

// ---------------- MFMA MLP -> dense d[s*M+m][r][f] bf16 (clamped at 0) -----
// One wave per (s, half-of-r, group of MPW m). Fully in-register; w2 columns
// pre-permuted by tau so layer-1's packed relu output IS the layer-2 B frag.
// launch_bounds(,2): keep weight/bias fragments resident (R6's 44-VGPR
// allocation forced per-iteration reloads).
__global__ __launch_bounds__(256, 2)
void mlp_store(const unsigned short* __restrict__ inT2,
               const unsigned short* __restrict__ w1bf,
               const unsigned short* __restrict__ w2bf,
               const float* __restrict__ b1, const float* __restrict__ b2,
               const int* __restrict__ ind0, const int* __restrict__ ind1,
               const int* __restrict__ ind2, const int* __restrict__ mix,
               const int* __restrict__ inv,
               unsigned short* __restrict__ dbuf) {
    int t    = threadIdx.x;
    int wave = t >> 6, lane = t & 63;
    int lo = lane & 15, q = lane >> 4;

    int wid  = blockIdx.x * 4 + wave;    // 0..6143
    int mgrp = wid & 1023;
    int half = (wid >> 10) & 1;
    int s_   = wid >> 11;
    int m0   = mgrp * MPW;

    short8 A1[4], A2[2];
#pragma unroll
    for (int tt = 0; tt < 4; tt++)
        A1[tt] = *(const short8*)(w1bf + ((16 * tt + lo) << 5) + (q << 3));
#pragma unroll
    for (int kk = 0; kk < 2; kk++)
        A2[kk] = *(const short8*)(w2bf + (lo << 6) + (kk << 5) + (q << 3));

    // biases as MFMA C-operand fragments
    f32x4 bbv[4];
#pragma unroll
    for (int tt = 0; tt < 4; tt++)
#pragma unroll
        for (int rg = 0; rg < 4; rg++)
            bbv[tt][rg] = b1[16 * tt + 4 * q + rg];
    f32x4 b2f;
#pragma unroll
    for (int rg = 0; rg < 4; rg++) {
        int f = 4 * q + rg;
        b2f[rg] = (f < 8) ? b2[f] : 0.f;
    }

    // batched index chase: 3 rounds of MPW independent loads
    int gq[MPW] = {0, 0, 0, 0};
    if (q < 3) {
        int si = s_ * 3 + q;
        const int* indq = (q == 0 ? ind0 : (q == 1 ? ind1 : ind2)) + (size_t)s_ * NIND * 2;
        int mi[MPW], kk[MPW];
#pragma unroll
        for (int u = 0; u < MPW; u++) mi[u] = mix[(size_t)si * MDIM + m0 + u];
#pragma unroll
        for (int u = 0; u < MPW; u++) kk[u] = inv[(size_t)si * NIND + mi[u]];
#pragma unroll
        for (int u = 0; u < MPW; u++) gq[u] = indq[2 * kk[u] + 1];
    }
    const unsigned short* srcs[MPW];
#pragma unroll
    for (int u = 0; u < MPW; u++)
        srcs[u] = inT2 + ((size_t)gq[u] * RDIM + half * 128 + lo) * 8;

    unsigned short* dst = dbuf + (size_t)(s_ * MDIM + m0) * 2048 + half * 1024 + lo * 8 + q * 4;

    union U { unsigned int u[4]; short8 s; };
    const short8 zero8 = {0, 0, 0, 0, 0, 0, 0, 0};

    short8 Bcur = zero8;
    if (q < 3) Bcur = *(const short8*)srcs[0];
#pragma unroll
    for (int it = 0; it < MPW * 8; it++) {
        const int u = it >> 3, j = it & 7;
        short8 Bnext = Bcur;
        if (it < MPW * 8 - 1 && q < 3)
            Bnext = *(const short8*)(srcs[(it + 1) >> 3] + ((it + 1) & 7) * 128);

        f32x4 a0 = __builtin_amdgcn_mfma_f32_16x16x32_bf16(A1[0], Bcur, bbv[0], 0, 0, 0);
        f32x4 a1 = __builtin_amdgcn_mfma_f32_16x16x32_bf16(A1[1], Bcur, bbv[1], 0, 0, 0);
        f32x4 a2 = __builtin_amdgcn_mfma_f32_16x16x32_bf16(A1[2], Bcur, bbv[2], 0, 0, 0);
        f32x4 a3 = __builtin_amdgcn_mfma_f32_16x16x32_bf16(A1[3], Bcur, bbv[3], 0, 0, 0);

        // relu + pack: result IS the layer-2 B fragment (tau-permuted w2)
        U ba, bb;
        ba.u[0] = cvtpk(fmaxf(a0[0], 0.f), fmaxf(a0[1], 0.f));
        ba.u[1] = cvtpk(fmaxf(a0[2], 0.f), fmaxf(a0[3], 0.f));
        ba.u[2] = cvtpk(fmaxf(a1[0], 0.f), fmaxf(a1[1], 0.f));
        ba.u[3] = cvtpk(fmaxf(a1[2], 0.f), fmaxf(a1[3], 0.f));
        bb.u[0] = cvtpk(fmaxf(a2[0], 0.f), fmaxf(a2[1], 0.f));
        bb.u[1] = cvtpk(fmaxf(a2[2], 0.f), fmaxf(a2[3], 0.f));
        bb.u[2] = cvtpk(fmaxf(a3[0], 0.f), fmaxf(a3[1], 0.f));
        bb.u[3] = cvtpk(fmaxf(a3[2], 0.f), fmaxf(a3[3], 0.f));

        f32x4 o = __builtin_amdgcn_mfma_f32_16x16x32_bf16(A2[0], ba.s, b2f, 0, 0, 0);
        o = __builtin_amdgcn_mfma_f32_16x16x32_bf16(A2[1], bb.s, o, 0, 0, 0);

        if (q < 2) {   // store d (clamped at 0; negatives never beat zeros baseline)
            uint2 ov;
            ov.x = cvtpk(fmaxf(o[0], 0.f), fmaxf(o[1], 0.f));
            ov.y = cvtpk(fmaxf(o[2], 0.f), fmaxf(o[3], 0.f));
            *(uint2*)(dst + (size_t)u * 2048 + j * 128) = ov;
        }
        Bcur = Bnext;
    }
}

// ---------------- gather-max per dest column -> d_out [f][r][c] directly ------
// grid (CDIM/GC, 4); block owns GC columns x 64 rows (4 per thread).
// Max accumulated in packed bf16 via v_pk_max_u16 (valid: all d >= 0).
__global__ __launch_bounds__(256)
void gather_max_t(const unsigned short* __restrict__ dbuf, const int* __restrict__ cnt,
                  const int* __restrict__ list, float* __restrict__ out) {
    __shared__ float ldsT[8][16][20];   // [f][rloc][c] (20-pad)
    __shared__ int   mlist[GC][MAXL];
    __shared__ int   mcnt[GC];
    int c0 = blockIdx.x * GC;
    int t  = threadIdx.x;
    int tc = t >> 4, tr = t & 15;
    int c  = c0 + tc;

    if (tr == 0) {   // one builder thread per column: merge 9 buckets
        int n = 0;
        for (int si = 0; si < 9; si++) {
            int s = si / 3;
            int k = cnt[si * CDIM + c]; if (k > CAP) k = CAP;
            const int* lp = list + ((size_t)si * CDIM + c) * CAP;
            for (int e = 0; e < k && n < MAXL; e++)
                mlist[tc][n++] = s * MDIM + lp[e];
        }
        mcnt[tc] = n;
    }
    __syncthreads();
    int n = mcnt[tc];

    uint4 acc[4];
#pragma unroll
    for (int p = 0; p < 4; p++) acc[p] = make_uint4(0u, 0u, 0u, 0u);

    int rbase = blockIdx.y * 64 + tr;
    for (int e = 0; e < n; e++) {
        int idx = mlist[tc][e];
        const unsigned short* bp = dbuf + ((size_t)idx * RDIM + rbase) * 8;
        uint4 v0 = *(const uint4*)(bp);
        uint4 v1 = *(const uint4*)(bp + 16 * 8);
        uint4 v2 = *(const uint4*)(bp + 32 * 8);
        uint4 v3 = *(const uint4*)(bp + 48 * 8);
        acc[0].x = pkmaxu(acc[0].x, v0.x); acc[0].y = pkmaxu(acc[0].y, v0.y);
        acc[0].z = pkmaxu(acc[0].z, v0.z); acc[0].w = pkmaxu(acc[0].w, v0.w);
        acc[1].x = pkmaxu(acc[1].x, v1.x); acc[1].y = pkmaxu(acc[1].y, v1.y);
        acc[1].z = pkmaxu(acc[1].z, v1.z); acc[1].w = pkmaxu(acc[1].w, v1.w);
        acc[2].x = pkmaxu(acc[2].x, v2.x); acc[2].y = pkmaxu(acc[2].y, v2.y);
        acc[2].z = pkmaxu(acc[2].z, v2.z); acc[2].w = pkmaxu(acc[2].w, v2.w);
        acc[3].x = pkmaxu(acc[3].x, v3.x); acc[3].y = pkmaxu(acc[3].y, v3.y);
        acc[3].z = pkmaxu(acc[3].z, v3.z); acc[3].w = pkmaxu(acc[3].w, v3.w);
    }

#pragma unroll
    for (int p = 0; p < 4; p++) {
        if (p) __syncthreads();             // prior read pass done before refill
        ldsT[0][tr][tc] = __uint_as_float(acc[p].x << 16);
        ldsT[1][tr][tc] = __uint_as_float(acc[p].x & 0xffff0000u);
        ldsT[2][tr][tc] = __uint_as_float(acc[p].y << 16);
        ldsT[3][tr][tc] = __uint_as_float(acc[p].y & 0xffff0000u);
        ldsT[4][tr][tc] = __uint_as_float(acc[p].z << 16);
        ldsT[5][tr][tc] = __uint_as_float(acc[p].z & 0xffff0000u);
        ldsT[6][tr][tc] = __uint_as_float(acc[p].w << 16);
        ldsT[7][tr][tc] = __uint_as_float(acc[p].w & 0xffff0000u);
        __syncthreads();
#pragma unroll
        for (int k2 = 0; k2 < 2; k2++) {
            int idx2 = t * 2 + k2;                 // 0..511
            int f = idx2 >> 6, rl = (idx2 >> 2) & 15, cq = idx2 & 3;
            *(float4*)&out[((size_t)f * RDIM + blockIdx.y * 64 + p * 16 + rl) * CDIM + c0 + cq * 4] =
                *(const float4*)&ldsT[f][rl][cq * 4];
        }
    }
}

extern "C" void kernel_launch(void* const* d_in, const int* in_sizes, int n_in,
                              void* d_out, int out_size, void* d_ws, size_t ws_size,
                              hipStream_t stream) {
    const float* input = (const float*)d_in[0];
    const float* w1    = (const float*)d_in[1];
    const float* b1    = (const float*)d_in[2];
    const float* w2    = (const float*)d_in[3];
    const float* b2    = (const float*)d_in[4];
    const int*   ind0  = (const int*)d_in[5];
    const int*   ind1  = (const int*)d_in[6];
    const int*   ind2  = (const int*)d_in[7];
    const int*   mix   = (const int*)d_in[8];

    const size_t MiB = 1ull << 20;
    char* ws = (char*)d_ws;
    unsigned short* inT2 = (unsigned short*)ws;                    // 16 MiB
    unsigned short* dbuf = (unsigned short*)(ws + 16 * MiB);       // 48 MiB
    char* tail = ws + 64 * MiB;
    int* inv  = (int*)tail;                                        // 144 KiB
    int* cnt  = (int*)(tail + 147456);                             // 144 KiB
    int* list = (int*)(tail + 2 * 147456);                         // 2.25 MiB
    unsigned short* w1bf = (unsigned short*)(tail + 2 * 147456 + 9ull * CDIM * CAP * 4);
    unsigned short* w2bf = w1bf + 64 * 32;

    prep_in<<<dim3(CDIM / 32, RDIM / 32), 256, 0, stream>>>(input, inT2);
    build_inv<<<dim3(NIND / 256, 9), 256, 0, stream>>>(ind0, ind1, ind2, w1, w2,
                                                       inv, cnt, w1bf, w2bf);
    build_buckets<<<dim3(MDIM / 256, 9), 256, 0, stream>>>(ind0, ind1, ind2, mix, cnt, list);
    mlp_store<<<NSETS * 2 * (MDIM / MPW) / 4, 256, 0, stream>>>(inT2, w1bf, w2bf, b1, b2,
                                                                ind0, ind1, ind2, mix, inv, dbuf);
    gather_max_t<<<dim3(CDIM / GC, 4), 256, 0, stream>>>(dbuf, cnt, list, (float*)d_out);
}

// Round 8
// 88.281 us; speedup vs baseline: 3.6663x; 1.0653x over previous
//
#include <hip/hip_runtime.h>
#include <cstdint>

#define F_IN   8
#define HID    64
#define F_OUTD 8
#define RDIM   256
#define CDIM   4096
#define NSETS  3
#define NIND   4096
#define MDIM   4096
#define MAXL   64
#define GC     16
#define MPW    4

using short8 = __attribute__((ext_vector_type(8))) short;
using f32x4  = __attribute__((ext_vector_type(4))) float;

// hardware packed f32->bf16 (RNE), low word = a
__device__ inline unsigned int cvtpk(float a, float b) {
    unsigned int r;
    asm("v_cvt_pk_bf16_f32 %0, %1, %2" : "=v"(r) : "v"(a), "v"(b));
    return r;
}
// packed unsigned 16-bit max (== bf16 max for nonnegative values)
__device__ inline unsigned int pkmaxu(unsigned int a, unsigned int b) {
    unsigned int r;
    asm("v_pk_max_u16 %0, %1, %2" : "=v"(r) : "v"(a), "v"(b));
    return r;
}

// ---------------- input prep: in [F][R][C] f32 -> inT2 [C][R][F] bf16 ----------
__global__ __launch_bounds__(256)
void prep_in(const float* __restrict__ in, unsigned short* __restrict__ out) {
    const int PADH = 264;                       // halfs per c-row (528B)
    __shared__ unsigned short tile[32 * PADH];
    int c0 = blockIdx.x * 32, r0 = blockIdx.y * 32;
    int t = threadIdx.x;
    int tx = t & 31, ty = t >> 5;
#pragma unroll
    for (int f = 0; f < 8; f += 2)
#pragma unroll
        for (int rr = 0; rr < 4; rr++) {
            int r = ty + rr * 8;
            float v0 = in[((size_t)f * RDIM + (r0 + r)) * CDIM + c0 + tx];
            float v1 = in[((size_t)(f + 1) * RDIM + (r0 + r)) * CDIM + c0 + tx];
            *(unsigned int*)&tile[tx * PADH + r * 8 + f] = cvtpk(v0, v1);
        }
    __syncthreads();
    int r = t & 31, cl = t >> 5;
#pragma unroll
    for (int cc = 0; cc < 4; cc++) {
        int c = cc * 8 + cl;
        uint4 v = *(const uint4*)&tile[c * PADH + r * 8];
        *(uint4*)(out + (((size_t)(c0 + c) * RDIM) + (r0 + r)) * 8) = v;
    }
}

// ---------------- setup: inverse perms + mergecnt zero + weight prep ----------
// inv[si][c0]=k s.t. ind_i[s][k][0]==c0; block (0,0) converts weights to bf16.
// w2's columns are permuted by tau so that layer-1's packed relu output
// (D-fragment order) is directly the layer-2 B-fragment:
//   tau(32*hi + 8*q + e) = 32*hi + 16*(e>>2) + 4*q + (e&3)
__global__ void build_inv(const int* __restrict__ ind0, const int* __restrict__ ind1,
                          const int* __restrict__ ind2,
                          const float* __restrict__ w1, const float* __restrict__ w2,
                          int* __restrict__ inv, int* __restrict__ mergecnt,
                          unsigned short* __restrict__ w1bf, unsigned short* __restrict__ w2bf) {
    int k  = blockIdx.x * 256 + threadIdx.x;
    int si = blockIdx.y;
    int s_ = si / 3, i_ = si % 3;
    const int* ind = (i_ == 0 ? ind0 : (i_ == 1 ? ind1 : ind2)) + (size_t)s_ * NIND * 2;
    int c0 = ind[2 * k];
    inv[(size_t)si * NIND + c0] = k;
    if (si == 0) mergecnt[k] = 0;
    if (blockIdx.x == 0 && blockIdx.y == 0) {
        int t = threadIdx.x;
        for (int i = t; i < 64 * 32; i += 256) {
            int j = i >> 5, kk = i & 31;
            w1bf[i] = (kk < 24) ? (unsigned short)(cvtpk(w1[j * 24 + kk], 0.f) & 0xffff) : 0;
        }
        for (int i = t; i < 16 * 64; i += 256) {
            int f = i >> 6, kg = i & 63;
            int hi = kg >> 5, q = (kg >> 3) & 3, e = kg & 7;
            int j = (hi << 5) + ((e >> 2) << 4) + (q << 2) + (e & 3);   // tau
            w2bf[i] = (f < 8) ? (unsigned short)(cvtpk(w2[f * 64 + j], 0.f) & 0xffff) : 0;
        }
    }
}

// ---------------- bucket-invert the scatter into ONE merged list per column --
// mergelist[c][slot] = s*MDIM + m  (the d-tile index contributing to column c)
__global__ void build_buckets(const int* __restrict__ ind0, const int* __restrict__ ind1,
                              const int* __restrict__ ind2, const int* __restrict__ mix,
                              int* __restrict__ mergecnt, int* __restrict__ mergelist) {
    int m  = blockIdx.x * 256 + threadIdx.x;
    int si = blockIdx.y;
    int s_ = si / 3, i_ = si % 3;
    const int* ind = (i_ == 0 ? ind0 : (i_ == 1 ? ind1 : ind2)) + (size_t)s_ * NIND * 2;
    int mi = mix[(size_t)si * MDIM + m];
    int c  = ind[2 * mi + 1];
    int slot = atomicAdd(&mergecnt[c], 1);
    if (slot < MAXL) mergelist[(size_t)c * MAXL + slot] = s_ * MDIM + m;
}

// ---------------- MFMA MLP -> dense d[s*M+m][r][f] bf16 (clamped at 0) -----
// One wave per (s, half-of-r, group of MPW m). Fully in-register; w2 columns
// pre-permuted by tau so layer-1's packed relu output IS the layer-2 B frag.
__global__ __launch_bounds__(256, 2)
void mlp_store(const unsigned short* __restrict__ inT2,
               const unsigned short* __restrict__ w1bf,
               const unsigned short* __restrict__ w2bf,
               const float* __restrict__ b1, const float* __restrict__ b2,
               const int* __restrict__ ind0, const int* __restrict__ ind1,
               const int* __restrict__ ind2, const int* __restrict__ mix,
               const int* __restrict__ inv,
               unsigned short* __restrict__ dbuf) {
    int t    = threadIdx.x;
    int wave = t >> 6, lane = t & 63;
    int lo = lane & 15, q = lane >> 4;

    int wid  = blockIdx.x * 4 + wave;    // 0..6143
    int mgrp = wid & 1023;
    int half = (wid >> 10) & 1;
    int s_   = wid >> 11;
    int m0   = mgrp * MPW;

    short8 A1[4], A2[2];
#pragma unroll
    for (int tt = 0; tt < 4; tt++)
        A1[tt] = *(const short8*)(w1bf + ((16 * tt + lo) << 5) + (q << 3));
#pragma unroll
    for (int kk = 0; kk < 2; kk++)
        A2[kk] = *(const short8*)(w2bf + (lo << 6) + (kk << 5) + (q << 3));

    // biases as MFMA C-operand fragments
    f32x4 bbv[4];
#pragma unroll
    for (int tt = 0; tt < 4; tt++)
#pragma unroll
        for (int rg = 0; rg < 4; rg++)
            bbv[tt][rg] = b1[16 * tt + 4 * q + rg];
    f32x4 b2f;
#pragma unroll
    for (int rg = 0; rg < 4; rg++) {
        int f = 4 * q + rg;
        b2f[rg] = (f < 8) ? b2[f] : 0.f;
    }

    // batched index chase: 3 rounds of MPW independent loads
    int gq[MPW] = {0, 0, 0, 0};
    if (q < 3) {
        int si = s_ * 3 + q;
        const int* indq = (q == 0 ? ind0 : (q == 1 ? ind1 : ind2)) + (size_t)s_ * NIND * 2;
        int mi[MPW], kk[MPW];
#pragma unroll
        for (int u = 0; u < MPW; u++) mi[u] = mix[(size_t)si * MDIM + m0 + u];
#pragma unroll
        for (int u = 0; u < MPW; u++) kk[u] = inv[(size_t)si * NIND + mi[u]];
#pragma unroll
        for (int u = 0; u < MPW; u++) gq[u] = indq[2 * kk[u] + 1];
    }
    const unsigned short* srcs[MPW];
#pragma unroll
    for (int u = 0; u < MPW; u++)
        srcs[u] = inT2 + ((size_t)gq[u] * RDIM + half * 128 + lo) * 8;

    unsigned short* dst = dbuf + (size_t)(s_ * MDIM + m0) * 2048 + half * 1024 + lo * 8 + q * 4;

    union U { unsigned int u[4]; short8 s; };
    const short8 zero8 = {0, 0, 0, 0, 0, 0, 0, 0};

    short8 Bcur = zero8;
    if (q < 3) Bcur = *(const short8*)srcs[0];
#pragma unroll
    for (int it = 0; it < MPW * 8; it++) {
        const int u = it >> 3, j = it & 7;
        short8 Bnext = Bcur;
        if (it < MPW * 8 - 1 && q < 3)
            Bnext = *(const short8*)(srcs[(it + 1) >> 3] + ((it + 1) & 7) * 128);

        f32x4 a0 = __builtin_amdgcn_mfma_f32_16x16x32_bf16(A1[0], Bcur, bbv[0], 0, 0, 0);
        f32x4 a1 = __builtin_amdgcn_mfma_f32_16x16x32_bf16(A1[1], Bcur, bbv[1], 0, 0, 0);
        f32x4 a2 = __builtin_amdgcn_mfma_f32_16x16x32_bf16(A1[2], Bcur, bbv[2], 0, 0, 0);
        f32x4 a3 = __builtin_amdgcn_mfma_f32_16x16x32_bf16(A1[3], Bcur, bbv[3], 0, 0, 0);

        // relu + pack: result IS the layer-2 B fragment (tau-permuted w2)
        U ba, bb;
        ba.u[0] = cvtpk(fmaxf(a0[0], 0.f), fmaxf(a0[1], 0.f));
        ba.u[1] = cvtpk(fmaxf(a0[2], 0.f), fmaxf(a0[3], 0.f));
        ba.u[2] = cvtpk(fmaxf(a1[0], 0.f), fmaxf(a1[1], 0.f));
        ba.u[3] = cvtpk(fmaxf(a1[2], 0.f), fmaxf(a1[3], 0.f));
        bb.u[0] = cvtpk(fmaxf(a2[0], 0.f), fmaxf(a2[1], 0.f));
        bb.u[1] = cvtpk(fmaxf(a2[2], 0.f), fmaxf(a2[3], 0.f));
        bb.u[2] = cvtpk(fmaxf(a3[0], 0.f), fmaxf(a3[1], 0.f));
        bb.u[3] = cvtpk(fmaxf(a3[2], 0.f), fmaxf(a3[3], 0.f));

        f32x4 o = __builtin_amdgcn_mfma_f32_16x16x32_bf16(A2[0], ba.s, b2f, 0, 0, 0);
        o = __builtin_amdgcn_mfma_f32_16x16x32_bf16(A2[1], bb.s, o, 0, 0, 0);

        if (q < 2) {   // store d (clamped at 0; negatives never beat zeros baseline)
            uint2 ov;
            ov.x = cvtpk(fmaxf(o[0], 0.f), fmaxf(o[1], 0.f));
            ov.y = cvtpk(fmaxf(o[2], 0.f), fmaxf(o[3], 0.f));
            *(uint2*)(dst + (size_t)u * 2048 + j * 128) = ov;
        }
        Bcur = Bnext;
    }
}

// ---------------- gather-max per dest column -> d_out [f][r][c] directly ------
// grid (CDIM/GC, 4); block owns GC columns x 64 rows (4 per thread).
// Merged list read cooperatively (no serial 9-bucket chase); 2-deep entry
// pipeline keeps 8 x 256B segments in flight per wave.
__global__ __launch_bounds__(256)
void gather_max_t(const unsigned short* __restrict__ dbuf, const int* __restrict__ mergecnt,
                  const int* __restrict__ mergelist, float* __restrict__ out) {
    __shared__ float ldsT[8][16][20];   // [f][rloc][c] (20-pad)
    __shared__ int   mlist[GC][MAXL];
    int c0 = blockIdx.x * GC;
    int t  = threadIdx.x;
    int tc = t >> 4, tr = t & 15;
    int c  = c0 + tc;

    int n = mergecnt[c]; if (n > MAXL) n = MAXL;
    for (int e = tr; e < n; e += 16)
        mlist[tc][e] = mergelist[(size_t)c * MAXL + e];
    __syncthreads();

    uint4 acc[4];
#pragma unroll
    for (int p = 0; p < 4; p++) acc[p] = make_uint4(0u, 0u, 0u, 0u);

    int rbase = blockIdx.y * 64 + tr;
    if (n > 0) {
        const unsigned short* bp = dbuf + ((size_t)mlist[tc][0] * RDIM + rbase) * 8;
        uint4 p0 = *(const uint4*)(bp);
        uint4 p1 = *(const uint4*)(bp + 16 * 8);
        uint4 p2 = *(const uint4*)(bp + 32 * 8);
        uint4 p3 = *(const uint4*)(bp + 48 * 8);
        for (int e = 1; e < n; e++) {
            const unsigned short* bq = dbuf + ((size_t)mlist[tc][e] * RDIM + rbase) * 8;
            uint4 q0 = *(const uint4*)(bq);
            uint4 q1 = *(const uint4*)(bq + 16 * 8);
            uint4 q2 = *(const uint4*)(bq + 32 * 8);
            uint4 q3 = *(const uint4*)(bq + 48 * 8);
            acc[0].x = pkmaxu(acc[0].x, p0.x); acc[0].y = pkmaxu(acc[0].y, p0.y);
            acc[0].z = pkmaxu(acc[0].z, p0.z); acc[0].w = pkmaxu(acc[0].w, p0.w);
            acc[1].x = pkmaxu(acc[1].x, p1.x); acc[1].y = pkmaxu(acc[1].y, p1.y);
            acc[1].z = pkmaxu(acc[1].z, p1.z); acc[1].w = pkmaxu(acc[1].w, p1.w);
            acc[2].x = pkmaxu(acc[2].x, p2.x); acc[2].y = pkmaxu(acc[2].y, p2.y);
            acc[2].z = pkmaxu(acc[2].z, p2.z); acc[2].w = pkmaxu(acc[2].w, p2.w);
            acc[3].x = pkmaxu(acc[3].x, p3.x); acc[3].y = pkmaxu(acc[3].y, p3.y);
            acc[3].z = pkmaxu(acc[3].z, p3.z); acc[3].w = pkmaxu(acc[3].w, p3.w);
            p0 = q0; p1 = q1; p2 = q2; p3 = q3;
        }
        acc[0].x = pkmaxu(acc[0].x, p0.x); acc[0].y = pkmaxu(acc[0].y, p0.y);
        acc[0].z = pkmaxu(acc[0].z, p0.z); acc[0].w = pkmaxu(acc[0].w, p0.w);
        acc[1].x = pkmaxu(acc[1].x, p1.x); acc[1].y = pkmaxu(acc[1].y, p1.y);
        acc[1].z = pkmaxu(acc[1].z, p1.z); acc[1].w = pkmaxu(acc[1].w, p1.w);
        acc[2].x = pkmaxu(acc[2].x, p2.x); acc[2].y = pkmaxu(acc[2].y, p2.y);
        acc[2].z = pkmaxu(acc[2].z, p2.z); acc[2].w = pkmaxu(acc[2].w, p2.w);
        acc[3].x = pkmaxu(acc[3].x, p3.x); acc[3].y = pkmaxu(acc[3].y, p3.y);
        acc[3].z = pkmaxu(acc[3].z, p3.z); acc[3].w = pkmaxu(acc[3].w, p3.w);
    }

#pragma unroll
    for (int p = 0; p < 4; p++) {
        if (p) __syncthreads();             // prior read pass done before refill
        ldsT[0][tr][tc] = __uint_as_float(acc[p].x << 16);
        ldsT[1][tr][tc] = __uint_as_float(acc[p].x & 0xffff0000u);
        ldsT[2][tr][tc] = __uint_as_float(acc[p].y << 16);
        ldsT[3][tr][tc] = __uint_as_float(acc[p].y & 0xffff0000u);
        ldsT[4][tr][tc] = __uint_as_float(acc[p].z << 16);
        ldsT[5][tr][tc] = __uint_as_float(acc[p].z & 0xffff0000u);
        ldsT[6][tr][tc] = __uint_as_float(acc[p].w << 16);
        ldsT[7][tr][tc] = __uint_as_float(acc[p].w & 0xffff0000u);
        __syncthreads();
#pragma unroll
        for (int k2 = 0; k2 < 2; k2++) {
            int idx2 = t * 2 + k2;                 // 0..511
            int f = idx2 >> 6, rl = (idx2 >> 2) & 15, cq = idx2 & 3;
            *(float4*)&out[((size_t)f * RDIM + blockIdx.y * 64 + p * 16 + rl) * CDIM + c0 + cq * 4] =
                *(const float4*)&ldsT[f][rl][cq * 4];
        }
    }
}

extern "C" void kernel_launch(void* const* d_in, const int* in_sizes, int n_in,
                              void* d_out, int out_size, void* d_ws, size_t ws_size,
                              hipStream_t stream) {
    const float* input = (const float*)d_in[0];
    const float* w1    = (const float*)d_in[1];
    const float* b1    = (const float*)d_in[2];
    const float* w2    = (const float*)d_in[3];
    const float* b2    = (const float*)d_in[4];
    const int*   ind0  = (const int*)d_in[5];
    const int*   ind1  = (const int*)d_in[6];
    const int*   ind2  = (const int*)d_in[7];
    const int*   mix   = (const int*)d_in[8];

    const size_t MiB = 1ull << 20;
    char* ws = (char*)d_ws;
    unsigned short* inT2 = (unsigned short*)ws;                    // 16 MiB
    unsigned short* dbuf = (unsigned short*)(ws + 16 * MiB);       // 48 MiB
    char* tail = ws + 64 * MiB;
    int* inv       = (int*)tail;                                   // 144 KiB
    int* mergecnt  = (int*)(tail + 147456);                        // 16 KiB
    int* mergelist = (int*)(tail + 147456 + 16384);                // 1 MiB
    unsigned short* w1bf = (unsigned short*)(tail + 147456 + 16384 + (size_t)CDIM * MAXL * 4);
    unsigned short* w2bf = w1bf + 64 * 32;

    prep_in<<<dim3(CDIM / 32, RDIM / 32), 256, 0, stream>>>(input, inT2);
    build_inv<<<dim3(NIND / 256, 9), 256, 0, stream>>>(ind0, ind1, ind2, w1, w2,
                                                       inv, mergecnt, w1bf, w2bf);
    build_buckets<<<dim3(MDIM / 256, 9), 256, 0, stream>>>(ind0, ind1, ind2, mix,
                                                           mergecnt, mergelist);
    mlp_store<<<NSETS * 2 * (MDIM / MPW) / 4, 256, 0, stream>>>(inT2, w1bf, w2bf, b1, b2,
                                                                ind0, ind1, ind2, mix, inv, dbuf);
    gather_max_t<<<dim3(CDIM / GC, 4), 256, 0, stream>>>(dbuf, mergecnt, mergelist,
                                                         (float*)d_out);
}